// Round 8
// baseline (558.816 us; speedup 1.0000x reference)
//
#include <hip/hip_runtime.h>
#include <math.h>

#define BB 4
#define CC 512
#define HH 48
#define WW 48
#define NN 2304      // H*W
#define DDQ 64       // C/8
#define LDSP 72      // padded LDS stride for 64-wide tiles (fp16 elems)
#define PW 50        // padded image width (W+2)
#define PROWS 2500   // (H+2)*(W+2)

typedef __attribute__((ext_vector_type(4))) float f32x4;
typedef __attribute__((ext_vector_type(8))) _Float16 half8;
typedef __attribute__((ext_vector_type(4))) _Float16 half4;
typedef __attribute__((ext_vector_type(8))) short bf16x8;

__device__ __forceinline__ int imax(int a, int b) { return a > b ? a : b; }
__device__ __forceinline__ int imin(int a, int b) { return a < b ? a : b; }
__device__ __forceinline__ int prow(int m) {
    int h = m / WW, w = m - h * WW;
    return (h + 1) * PW + (w + 1);
}
__device__ __forceinline__ unsigned short f2bf(float f) {
    unsigned u = __float_as_uint(f);
    u += 0x7fffu + ((u >> 16) & 1u);   // RNE
    return (unsigned short)(u >> 16);
}
__device__ __forceinline__ float bf2f(unsigned short s) {
    unsigned u = ((unsigned)s) << 16;
    return __uint_as_float(u);
}

// ---- async global->LDS, 16B per lane, wave-uniform LDS base ----
typedef __attribute__((address_space(1))) unsigned int g_u32;
typedef __attribute__((address_space(3))) unsigned int l_u32;
__device__ __forceinline__ void gl16(const void* g, void* l) {
    __builtin_amdgcn_global_load_lds((const g_u32*)g, (l_u32*)l, 16, 0, 0);
}

// Counted-vmcnt pipeline fences (T3+T4). 3-buffer pipeline, 6 loads/stage:
// steady state keeps TWO stages (12 loads) in flight across barriers.
#define WAIT12() asm volatile("s_waitcnt vmcnt(12)" ::: "memory")
#define WAIT6()  asm volatile("s_waitcnt vmcnt(6)" ::: "memory")
#define WAIT0()  asm volatile("s_waitcnt vmcnt(0)" ::: "memory")
#define BAR()    { __builtin_amdgcn_s_barrier(); asm volatile("" ::: "memory"); }

// XCD-chunked bijective swizzle (T1): 576 blocks, 8 XCDs, hw id raw -> XCD raw%8.
// wg = (raw%8)*72 + raw/8 gives each XCD a contiguous chunk of 72 logical blocks
// = 2 (i0,b) operand slabs x 36 j0 -> A slab + B slab fit the 4MB per-XCD L2.
#define BIG_DECODE()                                          \
    int raw = blockIdx.x;                                     \
    int wg = ((raw & 7) * 72) + (raw >> 3);                   \
    int jx = wg % 36; int rem = wg / 36;                      \
    int j0 = jx * 64, i0 = (rem & 3) * 128, b = rem >> 2;

// ===========================================================================
// Big-tile GEMM core: 128(M) x 64(N), BK=64 elems, 256 threads, XOR swizzle.
// ===========================================================================
#define BWAVE_IDX()                                  \
    int tid = threadIdx.x;                           \
    int wave = tid >> 6, lane = tid & 63;            \
    int wm = (wave >> 1) * 64, wn = (wave & 1) * 32; \
    int x = lane & 15, qq = lane >> 4;

__device__ __forceinline__ half8 fragld(const _Float16* T, int r, int c) {
    int kb = c ^ (r & 7);
    return *(const half8*)(T + r * 64 + kb * 8);
}
__device__ __forceinline__ bf16x8 fragld_b(const unsigned short* T, int r, int c) {
    int kb = c ^ (r & 7);
    return *(const bf16x8*)(T + r * 64 + kb * 8);
}

__device__ __forceinline__ void btile(const _Float16* As, const _Float16* Bs,
                                      f32x4 acc[4][2], int wm, int wn, int x, int qq) {
#pragma unroll
    for (int ks = 0; ks < 2; ++ks) {
        int c = ks * 4 + qq;
        half8 a0 = fragld(As, wm + x, c);
        half8 a1 = fragld(As, wm + 16 + x, c);
        half8 a2 = fragld(As, wm + 32 + x, c);
        half8 a3 = fragld(As, wm + 48 + x, c);
        half8 b0 = fragld(Bs, wn + x, c);
        half8 b1 = fragld(Bs, wn + 16 + x, c);
        acc[0][0] = __builtin_amdgcn_mfma_f32_16x16x32_f16(a0, b0, acc[0][0], 0, 0, 0);
        acc[0][1] = __builtin_amdgcn_mfma_f32_16x16x32_f16(a0, b1, acc[0][1], 0, 0, 0);
        acc[1][0] = __builtin_amdgcn_mfma_f32_16x16x32_f16(a1, b0, acc[1][0], 0, 0, 0);
        acc[1][1] = __builtin_amdgcn_mfma_f32_16x16x32_f16(a1, b1, acc[1][1], 0, 0, 0);
        acc[2][0] = __builtin_amdgcn_mfma_f32_16x16x32_f16(a2, b0, acc[2][0], 0, 0, 0);
        acc[2][1] = __builtin_amdgcn_mfma_f32_16x16x32_f16(a2, b1, acc[2][1], 0, 0, 0);
        acc[3][0] = __builtin_amdgcn_mfma_f32_16x16x32_f16(a3, b0, acc[3][0], 0, 0, 0);
        acc[3][1] = __builtin_amdgcn_mfma_f32_16x16x32_f16(a3, b1, acc[3][1], 0, 0, 0);
    }
}
__device__ __forceinline__ void btile_b(const unsigned short* As, const unsigned short* Bs,
                                        f32x4 acc[4][2], int wm, int wn, int x, int qq) {
#pragma unroll
    for (int ks = 0; ks < 2; ++ks) {
        int c = ks * 4 + qq;
        bf16x8 a0 = fragld_b(As, wm + x, c);
        bf16x8 a1 = fragld_b(As, wm + 16 + x, c);
        bf16x8 a2 = fragld_b(As, wm + 32 + x, c);
        bf16x8 a3 = fragld_b(As, wm + 48 + x, c);
        bf16x8 b0 = fragld_b(Bs, wn + x, c);
        bf16x8 b1 = fragld_b(Bs, wn + 16 + x, c);
        acc[0][0] = __builtin_amdgcn_mfma_f32_16x16x32_bf16(a0, b0, acc[0][0], 0, 0, 0);
        acc[0][1] = __builtin_amdgcn_mfma_f32_16x16x32_bf16(a0, b1, acc[0][1], 0, 0, 0);
        acc[1][0] = __builtin_amdgcn_mfma_f32_16x16x32_bf16(a1, b0, acc[1][0], 0, 0, 0);
        acc[1][1] = __builtin_amdgcn_mfma_f32_16x16x32_bf16(a1, b1, acc[1][1], 0, 0, 0);
        acc[2][0] = __builtin_amdgcn_mfma_f32_16x16x32_bf16(a2, b0, acc[2][0], 0, 0, 0);
        acc[2][1] = __builtin_amdgcn_mfma_f32_16x16x32_bf16(a2, b1, acc[2][1], 0, 0, 0);
        acc[3][0] = __builtin_amdgcn_mfma_f32_16x16x32_bf16(a3, b0, acc[3][0], 0, 0, 0);
        acc[3][1] = __builtin_amdgcn_mfma_f32_16x16x32_bf16(a3, b1, acc[3][1], 0, 0, 0);
    }
}

#define BACC_INIT()                                         \
    f32x4 zf = {0.f, 0.f, 0.f, 0.f};                        \
    f32x4 acc[4][2];                                        \
    _Pragma("unroll") for (int i_ = 0; i_ < 4; ++i_) {      \
        acc[i_][0] = zf; acc[i_][1] = zf; }

#define SLOT_A(i) int sb = (wave * 4 + (i)) * 64; int s = sb + lane; \
                  int r = s >> 3, kb = s & 7; int koff = ((kb ^ (r & 7)) << 3);
#define SLOT_B(i) int sb = (wave * 2 + (i)) * 64; int s = sb + lane; \
                  int r = s >> 3, kb = s & 7; int koff = ((kb ^ (r & 7)) << 3);

// ===========================================================================
// small 64^2 helpers
// ===========================================================================
__device__ __forceinline__ void stage_rows(_Float16* dst, const _Float16* __restrict__ src,
                                           int ld, int row0, int k0, int tid) {
#pragma unroll
    for (int i = 0; i < 2; ++i) {
        int s = tid * 2 + i;
        int r = s >> 3, off = (s & 7) << 3;
        *(half8*)(dst + r * LDSP + off) =
            *(const half8*)(src + (size_t)(row0 + r) * ld + k0 + off);
    }
}
__device__ __forceinline__ void mfma_tile(const _Float16* As, const _Float16* Bs,
                                          f32x4 acc[2][2], int wm, int wn, int x, int qq) {
#pragma unroll
    for (int ks = 0; ks < 2; ++ks) {
        int kof = ks * 32 + qq * 8;
        half8 a0 = *(const half8*)(As + (wm + x) * LDSP + kof);
        half8 a1 = *(const half8*)(As + (wm + 16 + x) * LDSP + kof);
        half8 b0 = *(const half8*)(Bs + (wn + x) * LDSP + kof);
        half8 b1 = *(const half8*)(Bs + (wn + 16 + x) * LDSP + kof);
        acc[0][0] = __builtin_amdgcn_mfma_f32_16x16x32_f16(a0, b0, acc[0][0], 0, 0, 0);
        acc[0][1] = __builtin_amdgcn_mfma_f32_16x16x32_f16(a0, b1, acc[0][1], 0, 0, 0);
        acc[1][0] = __builtin_amdgcn_mfma_f32_16x16x32_f16(a1, b0, acc[1][0], 0, 0, 0);
        acc[1][1] = __builtin_amdgcn_mfma_f32_16x16x32_f16(a1, b1, acc[1][1], 0, 0, 0);
    }
}
#define WAVE_IDX()                             \
    int tid = threadIdx.x;                     \
    int wave = tid >> 6, lane = tid & 63;      \
    int wm = (wave >> 1) * 32, wn = (wave & 1) * 32; \
    int x = lane & 15, qq = lane >> 4;
#define ACC_INIT()                             \
    f32x4 zf = {0.f, 0.f, 0.f, 0.f};           \
    f32x4 acc[2][2];                           \
    acc[0][0] = zf; acc[0][1] = zf; acc[1][0] = zf; acc[1][1] = zf;

// ------------------------- prep kernels -------------------------
__global__ __launch_bounds__(256) void k_cast_multi(const float* __restrict__ s0,
                                                    const float* __restrict__ s1,
                                                    const float* __restrict__ s2,
                                                    _Float16* __restrict__ d0,
                                                    _Float16* __restrict__ d1,
                                                    _Float16* __restrict__ d2, int n) {
    const float* s = blockIdx.y == 0 ? s0 : (blockIdx.y == 1 ? s1 : s2);
    _Float16* d = blockIdx.y == 0 ? d0 : (blockIdx.y == 1 ? d1 : d2);
    for (int i = blockIdx.x * 256 + threadIdx.x; i < n; i += gridDim.x * 256)
        d[i] = (_Float16)s[i];
}

__global__ __launch_bounds__(256) void k_repack_conv2(const float* __restrict__ w1,
                                                      const float* __restrict__ w2,
                                                      _Float16* __restrict__ d1,
                                                      _Float16* __restrict__ d2) {
    const float* w = blockIdx.y ? w2 : w1;
    _Float16* dst = blockIdx.y ? d2 : d1;
    int i = blockIdx.x * 256 + threadIdx.x;
    if (i >= 9 * CC * CC) return;
    int r = i / (CC * CC);
    int rem = i - r * CC * CC;
    int co = rem / CC, ci = rem - (rem / CC) * CC;
    dst[i] = (_Float16)w[((size_t)co * CC + ci) * 9 + r];
}

__global__ __launch_bounds__(256) void k_transpose_x(const float* __restrict__ x,
                                                     _Float16* __restrict__ xT) {
    __shared__ float tile[32][33];
    int b = blockIdx.z;
    int c0 = blockIdx.y * 32, n0 = blockIdx.x * 32;
    int tx = threadIdx.x & 31, ty = threadIdx.x >> 5;
    const float* xb = x + (size_t)b * CC * NN;
#pragma unroll
    for (int rr = 0; rr < 32; rr += 8)
        tile[ty + rr][tx] = xb[(size_t)(c0 + ty + rr) * NN + n0 + tx];
    __syncthreads();
    _Float16* xTb = xT + (size_t)b * NN * CC;
#pragma unroll
    for (int rr = 0; rr < 32; rr += 8)
        xTb[(size_t)(n0 + ty + rr) * CC + c0 + tx] = (_Float16)tile[tx][ty + rr];
}

// ------------------------- q/k projection -------------------------
__global__ __launch_bounds__(256) void k_qkproj(const _Float16* __restrict__ Wq,
                                                const _Float16* __restrict__ Wk,
                                                const float* __restrict__ bq,
                                                const float* __restrict__ bk,
                                                const _Float16* __restrict__ xT,
                                                _Float16* __restrict__ qT,
                                                _Float16* __restrict__ kT) {
    __shared__ _Float16 As[64 * LDSP];
    __shared__ _Float16 Bs[64 * LDSP];
    WAVE_IDX();
    int j0 = blockIdx.x * 64, b = blockIdx.z;
    const _Float16* Wp = blockIdx.y ? Wk : Wq;
    const float* bias = blockIdx.y ? bk : bq;
    _Float16* outT = blockIdx.y ? kT : qT;
    const _Float16* xTb = xT + (size_t)b * NN * CC;
    ACC_INIT();
    for (int kc = 0; kc < CC; kc += 64) {
        stage_rows(As, Wp, CC, 0, kc, tid);
        stage_rows(Bs, xTb, CC, j0, kc, tid);
        __syncthreads();
        mfma_tile(As, Bs, acc, wm, wn, x, qq);
        __syncthreads();
    }
#pragma unroll
    for (int ms = 0; ms < 2; ++ms) {
        int R0 = wm + ms * 16 + qq * 4;
#pragma unroll
        for (int ns = 0; ns < 2; ++ns) {
            int Ccol = j0 + wn + ns * 16 + x;
            half4 t;
            t.x = (_Float16)(acc[ms][ns][0] + bias[R0 + 0]);
            t.y = (_Float16)(acc[ms][ns][1] + bias[R0 + 1]);
            t.z = (_Float16)(acc[ms][ns][2] + bias[R0 + 2]);
            t.w = (_Float16)(acc[ms][ns][3] + bias[R0 + 3]);
            *(half4*)(outT + ((size_t)b * NN + Ccol) * DDQ + R0) = t;
        }
    }
}

// ------------------------- C x C GEMM, big tile (out: bf16) -------------------------
// 3-buffer counted-vmcnt pipeline: two stages in flight across barriers.
template <int EPI, int PAD>
__global__ __launch_bounds__(256) void k_cgemm(const _Float16* __restrict__ W,
                                               const float* __restrict__ bias,
                                               const _Float16* __restrict__ Bsrc,
                                               const _Float16* __restrict__ gateH,
                                               unsigned short* __restrict__ out) {
    __shared__ __align__(16) _Float16 As[3][128 * 64];
    __shared__ __align__(16) _Float16 Bs[3][64 * 64];
    BWAVE_IDX();
    BIG_DECODE();
    const _Float16* Bb = Bsrc + (size_t)b * (PAD ? (size_t)PROWS * CC : (size_t)NN * CC);

    const _Float16* aSrc[4]; int aOf[4];
#pragma unroll
    for (int i = 0; i < 4; ++i) {
        SLOT_A(i);
        aSrc[i] = W + (size_t)(i0 + r) * CC + koff;
        aOf[i] = sb * 8;
    }
    const _Float16* bSrc[2]; int bOf[2];
#pragma unroll
    for (int i = 0; i < 2; ++i) {
        SLOT_B(i);
        int row = PAD ? prow(j0 + r) : (j0 + r);
        bSrc[i] = Bb + (size_t)row * CC + koff;
        bOf[i] = sb * 8;
    }
    BACC_INIT();
#define STG_G(kc, nb)                                                          \
    { _Pragma("unroll") for (int i = 0; i < 4; ++i)                            \
          gl16(aSrc[i] + (kc), As[nb] + aOf[i]);                               \
      _Pragma("unroll") for (int i = 0; i < 2; ++i)                            \
          gl16(bSrc[i] + (kc), Bs[nb] + bOf[i]); }
#define GSTEP(t, nb)                                                           \
    { WAIT12(); BAR();                                                         \
      btile(As[nb], Bs[nb], acc, wm, wn, x, qq);                               \
      BAR(); STG_G(((t) + 3) * 64, nb); }
    // prologue: stages 0,1,2 into bufs 0,1,2
    STG_G(0, 0); STG_G(64, 1); STG_G(128, 2);
    // steps 0..4 (stage s lands in buf s%3)
    GSTEP(0, 0) GSTEP(1, 1) GSTEP(2, 2) GSTEP(3, 0) GSTEP(4, 1)
    WAIT12(); BAR();
    btile(As[2], Bs[2], acc, wm, wn, x, qq);   // step 5
    WAIT6(); BAR();
    btile(As[0], Bs[0], acc, wm, wn, x, qq);   // step 6
    WAIT0(); BAR();
    btile(As[1], Bs[1], acc, wm, wn, x, qq);   // step 7
#undef GSTEP
#undef STG_G
#pragma unroll
    for (int mt = 0; mt < 4; ++mt) {
        int R0 = i0 + wm + mt * 16 + qq * 4;
#pragma unroll
        for (int nt = 0; nt < 2; ++nt) {
            int Ccol = j0 + wn + nt * 16 + x;
            half4 gh;
            if (EPI == 1)
                gh = *(const half4*)(gateH + ((size_t)b * PROWS + prow(Ccol)) * CC + R0);
#pragma unroll
            for (int e = 0; e < 4; ++e) {
                float v = acc[mt][nt][e] + bias[R0 + e];
                size_t idx = ((size_t)b * CC + R0 + e) * NN + Ccol;
                if (EPI == 1) v = (float)gh[e] / (1.f + __expf(-v));
                out[idx] = f2bf(v);
            }
        }
    }
}

// ------------------------- energy -> exp -> bf16 + row sums -------------------------
__global__ __launch_bounds__(256) void k_exp(const _Float16* __restrict__ qT,
                                             const _Float16* __restrict__ kT,
                                             unsigned short* __restrict__ attnB,
                                             float* __restrict__ rowsum, int rad) {
    __shared__ _Float16 qs[64 * LDSP];
    __shared__ _Float16 ks[64 * LDSP];
    __shared__ unsigned short Eh[64 * 72];
    __shared__ float psum[512];
    WAVE_IDX();
    int j0 = blockIdx.x * 64, i0 = blockIdx.y * 64, b = blockIdx.z;
    if (rad > 0) {
        int hlo = i0 / WW, hhi = (i0 + 63) / WW;
        int h2lo = imax(0, hlo - rad), h2hi = imin(HH - 1, hhi + rad);
        int klo = (h2lo * WW) & ~63;
        int khi = imin(NN, ((h2hi + 1) * WW + 63) & ~63);
        if (j0 + 64 <= klo || j0 >= khi) return;
    }
    stage_rows(qs, qT + (size_t)b * NN * DDQ, DDQ, i0, 0, tid);
    stage_rows(ks, kT + (size_t)b * NN * DDQ, DDQ, j0, 0, tid);
    __syncthreads();
    ACC_INIT();
    mfma_tile(qs, ks, acc, wm, wn, x, qq);
#pragma unroll
    for (int ns = 0; ns < 2; ++ns) {
        int col = wn + ns * 16 + x;
        int gn = j0 + col;
        int hn = gn / WW, cn = gn % WW;
#pragma unroll
        for (int ms = 0; ms < 2; ++ms)
#pragma unroll
            for (int e = 0; e < 4; ++e) {
                int row = wm + ms * 16 + qq * 4 + e;
                int gm = i0 + row;
                bool valid = true;
                if (rad > 0) {
                    int dh = gm / WW - hn; if (dh < 0) dh = -dh;
                    int dc = gm % WW - cn; if (dc < 0) dc = -dc;
                    valid = (dh <= rad) && (dc <= rad);
                }
                float w = valid ? __expf(acc[ms][ns][e]) : 0.f;
                Eh[row * 72 + col] = f2bf(w);
            }
    }
    __syncthreads();
#pragma unroll
    for (int t = 0; t < 2; ++t) {
        int s = tid + t * 256;
        int r = s >> 3, cg = (s & 7) << 3;
        bf16x8 v = *(const bf16x8*)(Eh + r * 72 + cg);
        *(bf16x8*)(attnB + ((size_t)b * NN + i0 + r) * NN + j0 + cg) = v;
        float ss = 0.f;
#pragma unroll
        for (int j = 0; j < 8; ++j) ss += bf2f((unsigned short)v[j]);
        psum[s] = ss;
    }
    __syncthreads();
    if (tid < 64) {
        float tot = 0.f;
#pragma unroll
        for (int g = 0; g < 8; ++g) tot += psum[tid * 8 + g];
        atomicAdd(rowsum + (size_t)b * NN + i0 + tid, tot);
    }
}

// ------------------------- attention apply, big tile, bf16 -------------------------
// 3-buffer counted-vmcnt pipeline (runtime step count; nsteps >= 12 always).
__global__ __launch_bounds__(256) void k_attn(const unsigned short* __restrict__ A,
                                              const unsigned short* __restrict__ attnB,
                                              const float* __restrict__ rowsum,
                                              const float* __restrict__ resF,
                                              const _Float16* __restrict__ resH,
                                              const float* __restrict__ gamma,
                                              float* __restrict__ outF,
                                              _Float16* __restrict__ outT, int rad) {
    __shared__ __align__(16) unsigned short As[3][128 * 64];
    __shared__ __align__(16) unsigned short Bs[3][64 * 64];
    BWAVE_IDX();
    BIG_DECODE();
    int klo = 0, khi = NN;
    if (rad > 0) {
        int hlo = j0 / WW, hhi = (j0 + 63) / WW;
        int h2lo = imax(0, hlo - rad), h2hi = imin(HH - 1, hhi + rad);
        klo = (h2lo * WW) & ~63;
        khi = imin(NN, ((h2hi + 1) * WW + 63) & ~63);
    }
    const unsigned short* Ab = A + (size_t)b * CC * NN;
    const unsigned short* Tb = attnB + (size_t)b * NN * NN;

    const unsigned short* aSrc[4]; int aOf[4];
#pragma unroll
    for (int i = 0; i < 4; ++i) {
        SLOT_A(i);
        aSrc[i] = Ab + (size_t)(i0 + r) * NN + koff + klo;
        aOf[i] = sb * 8;
    }
    const unsigned short* bSrc[2]; int bOf[2];
#pragma unroll
    for (int i = 0; i < 2; ++i) {
        SLOT_B(i);
        bSrc[i] = Tb + (size_t)(j0 + r) * NN + koff + klo;
        bOf[i] = sb * 8;
    }
    BACC_INIT();
    int nsteps = (khi - klo) >> 6;
#define STG_T(kc, nb)                                                          \
    { _Pragma("unroll") for (int i = 0; i < 4; ++i)                            \
          gl16(aSrc[i] + (kc), As[nb] + aOf[i]);                               \
      _Pragma("unroll") for (int i = 0; i < 2; ++i)                            \
          gl16(bSrc[i] + (kc), Bs[nb] + bOf[i]); }
    STG_T(0, 0); STG_T(64, 1); STG_T(128, 2);
    int cur = 0;
    for (int t = 0; t + 3 < nsteps; ++t) {
        WAIT12(); BAR();
        btile_b(As[cur], Bs[cur], acc, wm, wn, x, qq);
        BAR();
        STG_T((t + 3) << 6, cur);
        cur = (cur == 2) ? 0 : cur + 1;
    }
    int c1 = (cur == 2) ? 0 : cur + 1;
    int c2 = (c1 == 2) ? 0 : c1 + 1;
    WAIT12(); BAR();
    btile_b(As[cur], Bs[cur], acc, wm, wn, x, qq);
    WAIT6(); BAR();
    btile_b(As[c1], Bs[c1], acc, wm, wn, x, qq);
    WAIT0(); BAR();
    btile_b(As[c2], Bs[c2], acc, wm, wn, x, qq);
#undef STG_T
    float g = gamma[0];
#pragma unroll
    for (int mt = 0; mt < 4; ++mt) {
        int R0 = i0 + wm + mt * 16 + qq * 4;
#pragma unroll
        for (int nt = 0; nt < 2; ++nt) {
            int Ccol = j0 + wn + nt * 16 + x;
            float linv = g / fmaxf(rowsum[(size_t)b * NN + Ccol], 1e-30f);
            float v[4];
            if (resH) {
                half4 rh = *(const half4*)(resH + ((size_t)b * PROWS + prow(Ccol)) * CC + R0);
#pragma unroll
                for (int e = 0; e < 4; ++e)
                    v[e] = acc[mt][nt][e] * linv + (float)rh[e];
            } else {
#pragma unroll
                for (int e = 0; e < 4; ++e)
                    v[e] = acc[mt][nt][e] * linv + resF[((size_t)b * CC + R0 + e) * NN + Ccol];
            }
            if (outT) {
                half4 t;
                t.x = (_Float16)v[0]; t.y = (_Float16)v[1];
                t.z = (_Float16)v[2]; t.w = (_Float16)v[3];
                *(half4*)(outT + ((size_t)b * PROWS + prow(Ccol)) * CC + R0) = t;
            }
            if (outF) {
#pragma unroll
                for (int e = 0; e < 4; ++e)
                    outF[((size_t)b * CC + R0 + e) * NN + Ccol] = v[e];
            }
        }
    }
}

// ------------------------- 3x3 conv, big tile, fused BN+ReLU -------------------------
// 3-buffer counted-vmcnt pipeline over the flattened 72 (tap x kc) steps.
// Main loop runs 69 steps in groups of 3 (static buffer parity); 3 epilogue steps.
__global__ __launch_bounds__(256) void k_conv3(const _Float16* __restrict__ Arep,
                                               const _Float16* __restrict__ Tpad,
                                               const float* __restrict__ bng,
                                               const float* __restrict__ bnb,
                                               const float* __restrict__ bnm,
                                               const float* __restrict__ bnv,
                                               float* __restrict__ outF,
                                               _Float16* __restrict__ outT) {
    __shared__ __align__(16) _Float16 As[3][128 * 64];
    __shared__ __align__(16) _Float16 Bs[3][64 * 64];
    BWAVE_IDX();
    BIG_DECODE();
    const _Float16* Tb = Tpad + (size_t)b * PROWS * CC;

    const _Float16* aBase[4]; int aOf[4];
#pragma unroll
    for (int i = 0; i < 4; ++i) {
        SLOT_A(i);
        aBase[i] = Arep + (size_t)(i0 + r) * CC + koff;
        aOf[i] = sb * 8;
    }
    const _Float16* bBase[2]; int bOf[2];
#pragma unroll
    for (int i = 0; i < 2; ++i) {
        SLOT_B(i);
        bBase[i] = Tb + (size_t)prow(j0 + r) * CC + koff;
        bOf[i] = sb * 8;
    }
    BACC_INIT();

#define STAGE_CONV(u, nb)                                                       \
    {                                                                           \
        int rt_ = (u) >> 3, ci_ = ((u) & 7) << 6;                               \
        int r3_ = rt_ / 3;                                                      \
        ptrdiff_t aoff_ = (ptrdiff_t)rt_ * (CC * CC) + ci_;                     \
        ptrdiff_t boff_ =                                                       \
            (ptrdiff_t)((r3_ - 1) * PW + (rt_ - r3_ * 3 - 1)) * CC + ci_;       \
        _Pragma("unroll") for (int i = 0; i < 4; ++i)                           \
            gl16(aBase[i] + aoff_, As[nb] + aOf[i]);                            \
        _Pragma("unroll") for (int i = 0; i < 2; ++i)                           \
            gl16(bBase[i] + boff_, Bs[nb] + bOf[i]);                            \
    }

    STAGE_CONV(0, 0); STAGE_CONV(1, 1); STAGE_CONV(2, 2);
    // main: 69 steps (t..t+2 read bufs 0,1,2; stages t+3..t+5 refill them)
#pragma unroll 1
    for (int t = 0; t < 69; t += 3) {
        WAIT12(); BAR();
        btile(As[0], Bs[0], acc, wm, wn, x, qq);
        BAR();
        STAGE_CONV(t + 3, 0);
        WAIT12(); BAR();
        btile(As[1], Bs[1], acc, wm, wn, x, qq);
        BAR();
        STAGE_CONV(t + 4, 1);
        WAIT12(); BAR();
        btile(As[2], Bs[2], acc, wm, wn, x, qq);
        BAR();
        STAGE_CONV(t + 5, 2);
    }
    // epilogue: steps 69,70,71 in bufs 0,1,2
    WAIT12(); BAR();
    btile(As[0], Bs[0], acc, wm, wn, x, qq);
    WAIT6(); BAR();
    btile(As[1], Bs[1], acc, wm, wn, x, qq);
    WAIT0(); BAR();
    btile(As[2], Bs[2], acc, wm, wn, x, qq);
#undef STAGE_CONV

#pragma unroll
    for (int mt = 0; mt < 4; ++mt) {
        int R0 = i0 + wm + mt * 16 + qq * 4;
        float sc[4], sh[4];
#pragma unroll
        for (int e = 0; e < 4; ++e) {
            sc[e] = bng[R0 + e] * rsqrtf(bnv[R0 + e] + 1e-5f);
            sh[e] = bnb[R0 + e] - bnm[R0 + e] * sc[e];
        }
#pragma unroll
        for (int nt = 0; nt < 2; ++nt) {
            int Ccol = j0 + wn + nt * 16 + x;
            float v[4];
#pragma unroll
            for (int e = 0; e < 4; ++e) {
                float t = acc[mt][nt][e] * sc[e] + sh[e];
                v[e] = t > 0.f ? t : 0.f;
            }
            if (outF) {
#pragma unroll
                for (int e = 0; e < 4; ++e)
                    outF[((size_t)b * CC + R0 + e) * NN + Ccol] = v[e];
            }
            half4 t4;
            t4.x = (_Float16)v[0]; t4.y = (_Float16)v[1];
            t4.z = (_Float16)v[2]; t4.w = (_Float16)v[3];
            *(half4*)(outT + ((size_t)b * PROWS + prow(Ccol)) * CC + R0) = t4;
        }
    }
}

// ---------------------------------------------------------------------------
extern "C" void kernel_launch(void* const* d_in, const int* in_sizes, int n_in,
                              void* d_out, int out_size, void* d_ws, size_t ws_size,
                              hipStream_t stream) {
    const float* xin  = (const float*)d_in[0];
    const float* Wq   = (const float*)d_in[1];
    const float* bq   = (const float*)d_in[2];
    const float* Wk   = (const float*)d_in[3];
    const float* bk   = (const float*)d_in[4];
    const float* Wv   = (const float*)d_in[5];
    const float* bv   = (const float*)d_in[6];
    const float* c1w  = (const float*)d_in[7];
    const float* bn1w = (const float*)d_in[8];
    const float* bn1b = (const float*)d_in[9];
    const float* bn1m = (const float*)d_in[10];
    const float* bn1v = (const float*)d_in[11];
    const float* c2w  = (const float*)d_in[12];
    const float* bn2w = (const float*)d_in[13];
    const float* bn2b = (const float*)d_in[14];
    const float* bn2m = (const float*)d_in[15];
    const float* bn2v = (const float*)d_in[16];
    const float* s1w  = (const float*)d_in[17];
    const float* s1b  = (const float*)d_in[18];
    const float* s2w  = (const float*)d_in[19];
    const float* s2b  = (const float*)d_in[20];
    const float* gamma  = (const float*)d_in[21];
    const float* gamma1 = (const float*)d_in[22];
    const float* gamma2 = (const float*)d_in[23];

    float* out = (float*)d_out;

    char* p = (char*)d_ws;
    unsigned short* attn = (unsigned short*)p; p += (size_t)BB * NN * NN * 2;  // 42.5 MB
    _Float16* xT    = (_Float16*)p; p += (size_t)BB * NN * CC * 2;      // 9.4 MB
    _Float16* qT    = (_Float16*)p; p += (size_t)BB * NN * DDQ * 2;
    _Float16* kT    = (_Float16*)p; p += (size_t)BB * NN * DDQ * 2;
    unsigned short* vsB = (unsigned short*)p; p += (size_t)BB * CC * NN * 2;  // 9.4 MB
    _Float16* TattnP= (_Float16*)p; p += (size_t)BB * PROWS * CC * 2;   // 10.2 MB
    _Float16* TconvP= (_Float16*)p; p += (size_t)BB * PROWS * CC * 2;   // 10.2 MB
    float*    rR    = (float*)p;    p += (size_t)BB * CC * NN * 4;      // 18.9 MB
    _Float16* wq_h  = (_Float16*)p; p += (size_t)DDQ * CC * 2;
    _Float16* wk_h  = (_Float16*)p; p += (size_t)DDQ * CC * 2;
    _Float16* wv_h  = (_Float16*)p; p += (size_t)CC * CC * 2;
    _Float16* s1_h  = (_Float16*)p; p += (size_t)CC * CC * 2;
    _Float16* s2_h  = (_Float16*)p; p += (size_t)CC * CC * 2;
    _Float16* crep1 = (_Float16*)p; p += (size_t)9 * CC * CC * 2;
    _Float16* crep2 = (_Float16*)p; p += (size_t)9 * CC * CC * 2;
    float*    rowsum= (float*)p;    p += (size_t)3 * BB * NN * 4;       // 110 KB (3 stages)

    dim3 blk(256);

    // zero padded activation borders + rowsums
    hipMemsetAsync(TattnP, 0, (size_t)BB * PROWS * CC * 2, stream);
    hipMemsetAsync(TconvP, 0, (size_t)BB * PROWS * CC * 2, stream);
    hipMemsetAsync(rowsum, 0, (size_t)3 * BB * NN * 4, stream);

    // ---- prep ----
    k_cast_multi<<<dim3(128, 2), blk, 0, stream>>>(Wq, Wk, nullptr, wq_h, wk_h, nullptr, DDQ * CC);
    k_cast_multi<<<dim3(1024, 3), blk, 0, stream>>>(Wv, s1w, s2w, wv_h, s1_h, s2_h, CC * CC);
    k_repack_conv2<<<dim3((9 * CC * CC + 255) / 256, 2), blk, 0, stream>>>(c1w, c2w, crep1, crep2);
    k_transpose_x<<<dim3(NN / 32, CC / 32, BB), blk, 0, stream>>>(xin, xT);

    dim3 gQK(NN / 64, 2, BB);
    dim3 gExp(NN / 64, NN / 64, BB);    // (36, 36, 4) = 5184 blocks
    dim3 gBig(576);                     // 1-D, XCD-chunk swizzled in-kernel

    float* rs0 = rowsum;
    float* rs1 = rowsum + (size_t)BB * NN;
    float* rs2 = rowsum + (size_t)2 * BB * NN;

    // projections
    k_qkproj<<<gQK, blk, 0, stream>>>(wq_h, wk_h, bq, bk, xT, qT, kT);
    k_cgemm<0, 0><<<gBig, blk, 0, stream>>>(wv_h, bv, xT, nullptr, vsB);

    // ---- stage 0: dense attention ----
    k_exp<<<gExp, blk, 0, stream>>>(qT, kT, attn, rs0, -1);
    k_attn<<<gBig, blk, 0, stream>>>(vsB, attn, rs0, xin, nullptr, gamma, nullptr, TattnP, -1);
    k_conv3<<<gBig, blk, 0, stream>>>(crep1, TattnP, bn1w, bn1b, bn1m, bn1v, nullptr, TconvP);

    // ---- stage 1: radius-6 masked attention ----
    k_cgemm<1, 1><<<gBig, blk, 0, stream>>>(s1_h, s1b, TconvP, TconvP, vsB);
    k_exp<<<gExp, blk, 0, stream>>>(qT, kT, attn, rs1, 6);
    k_attn<<<gBig, blk, 0, stream>>>(vsB, attn, rs1, nullptr, TconvP, gamma1, nullptr, TattnP, 6);
    k_conv3<<<gBig, blk, 0, stream>>>(crep2, TattnP, bn2w, bn2b, bn2m, bn2v, rR, TconvP);

    // ---- stage 2: radius-12 masked attention ----
    k_cgemm<1, 1><<<gBig, blk, 0, stream>>>(s2_h, s2b, TconvP, TconvP, vsB);
    k_exp<<<gExp, blk, 0, stream>>>(qT, kT, attn, rs2, 12);
    k_attn<<<gBig, blk, 0, stream>>>(vsB, attn, rs2, rR, nullptr, gamma2, out, nullptr, 12);
}

// Round 9
// 537.596 us; speedup vs baseline: 1.0395x; 1.0395x over previous
//
#include <hip/hip_runtime.h>
#include <math.h>

#define BB 4
#define CC 512
#define HH 48
#define WW 48
#define NN 2304      // H*W
#define DDQ 64       // C/8
#define LDSP 72      // padded LDS stride for 64-wide tiles (fp16 elems)
#define PW 50        // padded image width (W+2)
#define PROWS 2500   // (H+2)*(W+2)

typedef __attribute__((ext_vector_type(4))) float f32x4;
typedef __attribute__((ext_vector_type(8))) _Float16 half8;
typedef __attribute__((ext_vector_type(4))) _Float16 half4;
typedef __attribute__((ext_vector_type(8))) short bf16x8;

__device__ __forceinline__ int imax(int a, int b) { return a > b ? a : b; }
__device__ __forceinline__ int imin(int a, int b) { return a < b ? a : b; }
__device__ __forceinline__ int prow(int m) {
    int h = m / WW, w = m - h * WW;
    return (h + 1) * PW + (w + 1);
}
__device__ __forceinline__ unsigned short f2bf(float f) {
    unsigned u = __float_as_uint(f);
    u += 0x7fffu + ((u >> 16) & 1u);   // RNE
    return (unsigned short)(u >> 16);
}
__device__ __forceinline__ float bf2f(unsigned short s) {
    unsigned u = ((unsigned)s) << 16;
    return __uint_as_float(u);
}

// ---- async global->LDS, 16B per lane, wave-uniform LDS base ----
typedef __attribute__((address_space(1))) unsigned int g_u32;
typedef __attribute__((address_space(3))) unsigned int l_u32;
__device__ __forceinline__ void gl16(const void* g, void* l) {
    __builtin_amdgcn_global_load_lds((const g_u32*)g, (l_u32*)l, 16, 0, 0);
}

// Counted-vmcnt pipeline fences (T3+T4): loads stay in flight across barriers.
#define WAIT6()  asm volatile("s_waitcnt vmcnt(6)" ::: "memory")
#define WAIT0()  asm volatile("s_waitcnt vmcnt(0)" ::: "memory")
#define BAR()    { __builtin_amdgcn_s_barrier(); asm volatile("" ::: "memory"); }

// XCD-chunked bijective swizzle (T1): 576 blocks, 8 XCDs.
#define BIG_DECODE()                                          \
    int raw = blockIdx.x;                                     \
    int wg = ((raw & 7) * 72) + (raw >> 3);                   \
    int jx = wg % 36; int rem = wg / 36;                      \
    int j0 = jx * 64, i0 = (rem & 3) * 128, b = rem >> 2;

// ===========================================================================
// Big-tile GEMM core: 128(M) x 64(N), BK=64 elems, 256 threads, XOR swizzle.
// ===========================================================================
#define BWAVE_IDX()                                  \
    int tid = threadIdx.x;                           \
    int wave = tid >> 6, lane = tid & 63;            \
    int wm = (wave >> 1) * 64, wn = (wave & 1) * 32; \
    int x = lane & 15, qq = lane >> 4;

__device__ __forceinline__ half8 fragld(const _Float16* T, int r, int c) {
    int kb = c ^ (r & 7);
    return *(const half8*)(T + r * 64 + kb * 8);
}
__device__ __forceinline__ bf16x8 fragld_b(const unsigned short* T, int r, int c) {
    int kb = c ^ (r & 7);
    return *(const bf16x8*)(T + r * 64 + kb * 8);
}

__device__ __forceinline__ void btile(const _Float16* As, const _Float16* Bs,
                                      f32x4 acc[4][2], int wm, int wn, int x, int qq) {
#pragma unroll
    for (int ks = 0; ks < 2; ++ks) {
        int c = ks * 4 + qq;
        half8 a0 = fragld(As, wm + x, c);
        half8 a1 = fragld(As, wm + 16 + x, c);
        half8 a2 = fragld(As, wm + 32 + x, c);
        half8 a3 = fragld(As, wm + 48 + x, c);
        half8 b0 = fragld(Bs, wn + x, c);
        half8 b1 = fragld(Bs, wn + 16 + x, c);
        acc[0][0] = __builtin_amdgcn_mfma_f32_16x16x32_f16(a0, b0, acc[0][0], 0, 0, 0);
        acc[0][1] = __builtin_amdgcn_mfma_f32_16x16x32_f16(a0, b1, acc[0][1], 0, 0, 0);
        acc[1][0] = __builtin_amdgcn_mfma_f32_16x16x32_f16(a1, b0, acc[1][0], 0, 0, 0);
        acc[1][1] = __builtin_amdgcn_mfma_f32_16x16x32_f16(a1, b1, acc[1][1], 0, 0, 0);
        acc[2][0] = __builtin_amdgcn_mfma_f32_16x16x32_f16(a2, b0, acc[2][0], 0, 0, 0);
        acc[2][1] = __builtin_amdgcn_mfma_f32_16x16x32_f16(a2, b1, acc[2][1], 0, 0, 0);
        acc[3][0] = __builtin_amdgcn_mfma_f32_16x16x32_f16(a3, b0, acc[3][0], 0, 0, 0);
        acc[3][1] = __builtin_amdgcn_mfma_f32_16x16x32_f16(a3, b1, acc[3][1], 0, 0, 0);
    }
}

#define BACC_INIT()                                         \
    f32x4 zf = {0.f, 0.f, 0.f, 0.f};                        \
    f32x4 acc[4][2];                                        \
    _Pragma("unroll") for (int i_ = 0; i_ < 4; ++i_) {      \
        acc[i_][0] = zf; acc[i_][1] = zf; }

#define SLOT_A(i) int sb = (wave * 4 + (i)) * 64; int s = sb + lane; \
                  int r = s >> 3, kb = s & 7; int koff = ((kb ^ (r & 7)) << 3);
#define SLOT_B(i) int sb = (wave * 2 + (i)) * 64; int s = sb + lane; \
                  int r = s >> 3, kb = s & 7; int koff = ((kb ^ (r & 7)) << 3);

// ===========================================================================
// small 64^2 helpers
// ===========================================================================
__device__ __forceinline__ void stage_rows(_Float16* dst, const _Float16* __restrict__ src,
                                           int ld, int row0, int k0, int tid) {
#pragma unroll
    for (int i = 0; i < 2; ++i) {
        int s = tid * 2 + i;
        int r = s >> 3, off = (s & 7) << 3;
        *(half8*)(dst + r * LDSP + off) =
            *(const half8*)(src + (size_t)(row0 + r) * ld + k0 + off);
    }
}
__device__ __forceinline__ void mfma_tile(const _Float16* As, const _Float16* Bs,
                                          f32x4 acc[2][2], int wm, int wn, int x, int qq) {
#pragma unroll
    for (int ks = 0; ks < 2; ++ks) {
        int kof = ks * 32 + qq * 8;
        half8 a0 = *(const half8*)(As + (wm + x) * LDSP + kof);
        half8 a1 = *(const half8*)(As + (wm + 16 + x) * LDSP + kof);
        half8 b0 = *(const half8*)(Bs + (wn + x) * LDSP + kof);
        half8 b1 = *(const half8*)(Bs + (wn + 16 + x) * LDSP + kof);
        acc[0][0] = __builtin_amdgcn_mfma_f32_16x16x32_f16(a0, b0, acc[0][0], 0, 0, 0);
        acc[0][1] = __builtin_amdgcn_mfma_f32_16x16x32_f16(a0, b1, acc[0][1], 0, 0, 0);
        acc[1][0] = __builtin_amdgcn_mfma_f32_16x16x32_f16(a1, b0, acc[1][0], 0, 0, 0);
        acc[1][1] = __builtin_amdgcn_mfma_f32_16x16x32_f16(a1, b1, acc[1][1], 0, 0, 0);
    }
}
#define WAVE_IDX()                             \
    int tid = threadIdx.x;                     \
    int wave = tid >> 6, lane = tid & 63;      \
    int wm = (wave >> 1) * 32, wn = (wave & 1) * 32; \
    int x = lane & 15, qq = lane >> 4;
#define ACC_INIT()                             \
    f32x4 zf = {0.f, 0.f, 0.f, 0.f};           \
    f32x4 acc[2][2];                           \
    acc[0][0] = zf; acc[0][1] = zf; acc[1][0] = zf; acc[1][1] = zf;

// ------------------------- prep kernels -------------------------
__global__ __launch_bounds__(256) void k_cast_multi(const float* __restrict__ s0,
                                                    const float* __restrict__ s1,
                                                    const float* __restrict__ s2,
                                                    _Float16* __restrict__ d0,
                                                    _Float16* __restrict__ d1,
                                                    _Float16* __restrict__ d2, int n) {
    const float* s = blockIdx.y == 0 ? s0 : (blockIdx.y == 1 ? s1 : s2);
    _Float16* d = blockIdx.y == 0 ? d0 : (blockIdx.y == 1 ? d1 : d2);
    for (int i = blockIdx.x * 256 + threadIdx.x; i < n; i += gridDim.x * 256)
        d[i] = (_Float16)s[i];
}

__global__ __launch_bounds__(256) void k_repack_conv2(const float* __restrict__ w1,
                                                      const float* __restrict__ w2,
                                                      _Float16* __restrict__ d1,
                                                      _Float16* __restrict__ d2) {
    const float* w = blockIdx.y ? w2 : w1;
    _Float16* dst = blockIdx.y ? d2 : d1;
    int i = blockIdx.x * 256 + threadIdx.x;
    if (i >= 9 * CC * CC) return;
    int r = i / (CC * CC);
    int rem = i - r * CC * CC;
    int co = rem / CC, ci = rem - (rem / CC) * CC;
    dst[i] = (_Float16)w[((size_t)co * CC + ci) * 9 + r];
}

__global__ __launch_bounds__(256) void k_transpose_x(const float* __restrict__ x,
                                                     _Float16* __restrict__ xT) {
    __shared__ float tile[32][33];
    int b = blockIdx.z;
    int c0 = blockIdx.y * 32, n0 = blockIdx.x * 32;
    int tx = threadIdx.x & 31, ty = threadIdx.x >> 5;
    const float* xb = x + (size_t)b * CC * NN;
#pragma unroll
    for (int rr = 0; rr < 32; rr += 8)
        tile[ty + rr][tx] = xb[(size_t)(c0 + ty + rr) * NN + n0 + tx];
    __syncthreads();
    _Float16* xTb = xT + (size_t)b * NN * CC;
#pragma unroll
    for (int rr = 0; rr < 32; rr += 8)
        xTb[(size_t)(n0 + ty + rr) * CC + c0 + tx] = (_Float16)tile[tx][ty + rr];
}

// ------------------------- q/k projection -------------------------
__global__ __launch_bounds__(256) void k_qkproj(const _Float16* __restrict__ Wq,
                                                const _Float16* __restrict__ Wk,
                                                const float* __restrict__ bq,
                                                const float* __restrict__ bk,
                                                const _Float16* __restrict__ xT,
                                                _Float16* __restrict__ qT,
                                                _Float16* __restrict__ kT) {
    __shared__ _Float16 As[64 * LDSP];
    __shared__ _Float16 Bs[64 * LDSP];
    WAVE_IDX();
    int j0 = blockIdx.x * 64, b = blockIdx.z;
    const _Float16* Wp = blockIdx.y ? Wk : Wq;
    const float* bias = blockIdx.y ? bk : bq;
    _Float16* outT = blockIdx.y ? kT : qT;
    const _Float16* xTb = xT + (size_t)b * NN * CC;
    ACC_INIT();
    for (int kc = 0; kc < CC; kc += 64) {
        stage_rows(As, Wp, CC, 0, kc, tid);
        stage_rows(Bs, xTb, CC, j0, kc, tid);
        __syncthreads();
        mfma_tile(As, Bs, acc, wm, wn, x, qq);
        __syncthreads();
    }
#pragma unroll
    for (int ms = 0; ms < 2; ++ms) {
        int R0 = wm + ms * 16 + qq * 4;
#pragma unroll
        for (int ns = 0; ns < 2; ++ns) {
            int Ccol = j0 + wn + ns * 16 + x;
            half4 t;
            t.x = (_Float16)(acc[ms][ns][0] + bias[R0 + 0]);
            t.y = (_Float16)(acc[ms][ns][1] + bias[R0 + 1]);
            t.z = (_Float16)(acc[ms][ns][2] + bias[R0 + 2]);
            t.w = (_Float16)(acc[ms][ns][3] + bias[R0 + 3]);
            *(half4*)(outT + ((size_t)b * NN + Ccol) * DDQ + R0) = t;
        }
    }
}

// ------------------------- C x C GEMM, big tile (out: bf16) -------------------------
// (exact r5 structure: 2-buffer counted-vmcnt 2-deep pipeline)
template <int EPI, int PAD>
__global__ __launch_bounds__(256) void k_cgemm(const _Float16* __restrict__ W,
                                               const float* __restrict__ bias,
                                               const _Float16* __restrict__ Bsrc,
                                               const _Float16* __restrict__ gateH,
                                               unsigned short* __restrict__ out) {
    __shared__ __align__(16) _Float16 As[2][128 * 64];
    __shared__ __align__(16) _Float16 Bs[2][64 * 64];
    BWAVE_IDX();
    BIG_DECODE();
    const _Float16* Bb = Bsrc + (size_t)b * (PAD ? (size_t)PROWS * CC : (size_t)NN * CC);

    const _Float16* aSrc[4]; int aOf[4];
#pragma unroll
    for (int i = 0; i < 4; ++i) {
        SLOT_A(i);
        aSrc[i] = W + (size_t)(i0 + r) * CC + koff;
        aOf[i] = sb * 8;
    }
    const _Float16* bSrc[2]; int bOf[2];
#pragma unroll
    for (int i = 0; i < 2; ++i) {
        SLOT_B(i);
        int row = PAD ? prow(j0 + r) : (j0 + r);
        bSrc[i] = Bb + (size_t)row * CC + koff;
        bOf[i] = sb * 8;
    }
    BACC_INIT();
#define STG_G(kc, nb)                                                          \
    { _Pragma("unroll") for (int i = 0; i < 4; ++i)                            \
          gl16(aSrc[i] + (kc), As[nb] + aOf[i]);                               \
      _Pragma("unroll") for (int i = 0; i < 2; ++i)                            \
          gl16(bSrc[i] + (kc), Bs[nb] + bOf[i]); }
    STG_G(0, 0);
    STG_G(64, 1);
    const int NSTEP = CC / 64;   // 8
#pragma unroll
    for (int t = 0; t + 2 < NSTEP; ++t) {   // t = 0..5
        WAIT6();
        BAR();
        btile(As[t & 1], Bs[t & 1], acc, wm, wn, x, qq);
        BAR();
        STG_G((t + 2) * 64, (t & 1));
    }
    WAIT6();
    BAR();
    btile(As[(NSTEP - 2) & 1], Bs[(NSTEP - 2) & 1], acc, wm, wn, x, qq);
    WAIT0();
    BAR();
    btile(As[(NSTEP - 1) & 1], Bs[(NSTEP - 1) & 1], acc, wm, wn, x, qq);
#undef STG_G
#pragma unroll
    for (int mt = 0; mt < 4; ++mt) {
        int R0 = i0 + wm + mt * 16 + qq * 4;
#pragma unroll
        for (int nt = 0; nt < 2; ++nt) {
            int Ccol = j0 + wn + nt * 16 + x;
            half4 gh;
            if (EPI == 1)
                gh = *(const half4*)(gateH + ((size_t)b * PROWS + prow(Ccol)) * CC + R0);
#pragma unroll
            for (int e = 0; e < 4; ++e) {
                float v = acc[mt][nt][e] + bias[R0 + e];
                size_t idx = ((size_t)b * CC + R0 + e) * NN + Ccol;
                if (EPI == 1) v = (float)gh[e] / (1.f + __expf(-v));
                out[idx] = f2bf(v);
            }
        }
    }
}

// ------------------------- FUSED attention: QK^T -> exp -> PV -------------------------
// Per block (i0: 128 c-rows, j0: 64 out-cols/query-rows, b): loop n-chunks of 64:
//   stage vsB A-tile (4 slots) + kT K-tile (2 slots) [6 gl16 -> same WAIT6 pipeline]
//   QK: e[m][n] via MFMA (q in registers), exp+mask -> Eh (bf16, LDSP pad)
//   PV: acc += A-frags x Eh-frags. Rowsum accumulated in registers (no atomics).
// Replaces k_exp + k_attn; no attnB round-trip; window logic purely local.
__global__ __launch_bounds__(256) void k_fattn(const unsigned short* __restrict__ A,
                                               const _Float16* __restrict__ qT,
                                               const _Float16* __restrict__ kT,
                                               const float* __restrict__ resF,
                                               const _Float16* __restrict__ resH,
                                               const float* __restrict__ gamma,
                                               float* __restrict__ outF,
                                               _Float16* __restrict__ outT, int rad) {
    __shared__ __align__(16) unsigned short As[2][128 * 64];
    __shared__ __align__(16) _Float16 Ks[2][64 * 64];
    __shared__ __align__(16) unsigned short Eh[64 * 72];
    __shared__ float rsLDS[2][64];
    BWAVE_IDX();
    BIG_DECODE();
    // QK-phase wave mapping: 64x64 e-tile split 2x2, wave tile 32x32
    int qm = (wave >> 1) * 32, qn = (wave & 1) * 32;

    int klo = 0, khi = NN;
    if (rad > 0) {
        int hlo = j0 / WW, hhi = (j0 + 63) / WW;
        int h2lo = imax(0, hlo - rad), h2hi = imin(HH - 1, hhi + rad);
        klo = (h2lo * WW) & ~63;
        khi = imin(NN, ((h2hi + 1) * WW + 63) & ~63);
    }
    int nsteps = (khi - klo) >> 6;

    const unsigned short* Ab = A + (size_t)b * CC * NN;
    const unsigned short* aSrc[4]; int aOf[4];
#pragma unroll
    for (int i = 0; i < 4; ++i) {
        SLOT_A(i);
        aSrc[i] = Ab + (size_t)(i0 + r) * NN + koff + klo;
        aOf[i] = sb * 8;
    }
    const _Float16* kSrc[2]; int kOf[2];
#pragma unroll
    for (int i = 0; i < 2; ++i) {
        SLOT_B(i);
        kSrc[i] = kT + ((size_t)b * NN + klo + r) * DDQ + koff;
        kOf[i] = sb * 8;
    }
    // q fragments in registers: rows j0+qm+{0,16}+x, d-offsets ks*32+qq*8
    half8 qreg[2][2];
#pragma unroll
    for (int ms = 0; ms < 2; ++ms)
#pragma unroll
        for (int ks = 0; ks < 2; ++ks)
            qreg[ms][ks] = *(const half8*)(qT +
                ((size_t)b * NN + j0 + qm + ms * 16 + x) * DDQ + ks * 32 + qq * 8);
    // mask precompute for this thread's 8 e-rows (m = j0+qm+ms*16+qq*4+e)
    int mh[8], mw[8];
    if (rad > 0) {
#pragma unroll
        for (int idx = 0; idx < 8; ++idx) {
            int gm = j0 + qm + (idx >> 2) * 16 + qq * 4 + (idx & 3);
            mh[idx] = gm / WW; mw[idx] = gm - mh[idx] * WW;
        }
    }
    BACC_INIT();            // PV accumulator acc[4][2]
    float rs[2][4];
#pragma unroll
    for (int ms = 0; ms < 2; ++ms)
#pragma unroll
        for (int e = 0; e < 4; ++e) rs[ms][e] = 0.f;

#define STG_F(kc, nb)                                                          \
    { _Pragma("unroll") for (int i = 0; i < 4; ++i)                            \
          gl16(aSrc[i] + (kc), As[nb] + aOf[i]);                               \
      _Pragma("unroll") for (int i = 0; i < 2; ++i)                            \
          gl16(kSrc[i] + ((size_t)(kc) << 6), Ks[nb] + kOf[i]); }
// one fused step: QK -> exp -> Eh -> PV on buffer nb (n-chunk base nb0 = klo + t*64)
#define FSTEP_BODY(nb, tt)                                                     \
    {                                                                          \
        f32x4 ez = {0.f, 0.f, 0.f, 0.f};                                       \
        f32x4 eacc[2][2];                                                      \
        eacc[0][0] = ez; eacc[0][1] = ez; eacc[1][0] = ez; eacc[1][1] = ez;    \
        _Pragma("unroll") for (int ks = 0; ks < 2; ++ks) {                     \
            int c = ks * 4 + qq;                                               \
            half8 k0 = fragld(Ks[nb], qn + x, c);                              \
            half8 k1 = fragld(Ks[nb], qn + 16 + x, c);                         \
            eacc[0][0] = __builtin_amdgcn_mfma_f32_16x16x32_f16(               \
                qreg[0][ks], k0, eacc[0][0], 0, 0, 0);                         \
            eacc[0][1] = __builtin_amdgcn_mfma_f32_16x16x32_f16(               \
                qreg[0][ks], k1, eacc[0][1], 0, 0, 0);                         \
            eacc[1][0] = __builtin_amdgcn_mfma_f32_16x16x32_f16(               \
                qreg[1][ks], k0, eacc[1][0], 0, 0, 0);                         \
            eacc[1][1] = __builtin_amdgcn_mfma_f32_16x16x32_f16(               \
                qreg[1][ks], k1, eacc[1][1], 0, 0, 0);                         \
        }                                                                      \
        int nbase = klo + ((tt) << 6);                                         \
        _Pragma("unroll") for (int ns = 0; ns < 2; ++ns) {                     \
            int col = qn + ns * 16 + x;                                        \
            int gn = nbase + col;                                              \
            int hn = gn / WW, cn = gn - hn * WW;                               \
            _Pragma("unroll") for (int ms = 0; ms < 2; ++ms)                   \
                _Pragma("unroll") for (int e = 0; e < 4; ++e) {                \
                    int row = qm + ms * 16 + qq * 4 + e;                       \
                    bool valid = true;                                         \
                    if (rad > 0) {                                             \
                        int dh = mh[ms * 4 + e] - hn; if (dh < 0) dh = -dh;    \
                        int dc = mw[ms * 4 + e] - cn; if (dc < 0) dc = -dc;    \
                        valid = (dh <= rad) && (dc <= rad);                    \
                    }                                                          \
                    float w = valid ? __expf(eacc[ms][ns][e]) : 0.f;           \
                    unsigned short wb = f2bf(w);                               \
                    Eh[row * 72 + col] = wb;                                   \
                    rs[ms][e] += bf2f(wb);                                     \
                }                                                              \
        }                                                                      \
        BAR();                                                                 \
        _Pragma("unroll") for (int ks = 0; ks < 2; ++ks) {                     \
            int c = ks * 4 + qq;                                               \
            int kof = ks * 32 + qq * 8;                                        \
            bf16x8 a0 = fragld_b(As[nb], wm + x, c);                           \
            bf16x8 a1 = fragld_b(As[nb], wm + 16 + x, c);                      \
            bf16x8 a2 = fragld_b(As[nb], wm + 32 + x, c);                      \
            bf16x8 a3 = fragld_b(As[nb], wm + 48 + x, c);                      \
            bf16x8 b0 = *(const bf16x8*)(Eh + (wn + x) * 72 + kof);            \
            bf16x8 b1 = *(const bf16x8*)(Eh + (wn + 16 + x) * 72 + kof);       \
            acc[0][0] = __builtin_amdgcn_mfma_f32_16x16x32_bf16(a0, b0, acc[0][0], 0, 0, 0); \
            acc[0][1] = __builtin_amdgcn_mfma_f32_16x16x32_bf16(a0, b1, acc[0][1], 0, 0, 0); \
            acc[1][0] = __builtin_amdgcn_mfma_f32_16x16x32_bf16(a1, b0, acc[1][0], 0, 0, 0); \
            acc[1][1] = __builtin_amdgcn_mfma_f32_16x16x32_bf16(a1, b1, acc[1][1], 0, 0, 0); \
            acc[2][0] = __builtin_amdgcn_mfma_f32_16x16x32_bf16(a2, b0, acc[2][0], 0, 0, 0); \
            acc[2][1] = __builtin_amdgcn_mfma_f32_16x16x32_bf16(a2, b1, acc[2][1], 0, 0, 0); \
            acc[3][0] = __builtin_amdgcn_mfma_f32_16x16x32_bf16(a3, b0, acc[3][0], 0, 0, 0); \
            acc[3][1] = __builtin_amdgcn_mfma_f32_16x16x32_bf16(a3, b1, acc[3][1], 0, 0, 0); \
        }                                                                      \
    }

    STG_F(0, 0);
    STG_F(64, 1);
    for (int t = 0; t + 2 < nsteps; ++t) {
        WAIT6();
        BAR();                       // stage(t) landed for all waves
        FSTEP_BODY((t & 1), t);
        BAR();                       // As/Ks[t&1] + Eh free
        STG_F((t + 2) << 6, (t & 1));
    }
    WAIT6();
    BAR();
    FSTEP_BODY(((nsteps - 2) & 1), nsteps - 2);
    WAIT0();
    BAR();
    FSTEP_BODY(((nsteps - 1) & 1), nsteps - 1);
#undef FSTEP_BODY
#undef STG_F

    // rowsum: reduce rs over the 16 n-lanes (x), then combine the two n-half waves
#pragma unroll
    for (int ms = 0; ms < 2; ++ms)
#pragma unroll
        for (int e = 0; e < 4; ++e) {
            float v = rs[ms][e];
            v += __shfl_xor(v, 1);
            v += __shfl_xor(v, 2);
            v += __shfl_xor(v, 4);
            v += __shfl_xor(v, 8);
            rs[ms][e] = v;
        }
    BAR();                           // Eh reads done before reuse? (rsLDS separate; barrier for write/read order)
    if (x == 0) {
#pragma unroll
        for (int ms = 0; ms < 2; ++ms)
#pragma unroll
            for (int e = 0; e < 4; ++e)
                rsLDS[wave & 1][qm + ms * 16 + qq * 4 + e] = rs[ms][e];
    }
    BAR();
    float g = gamma[0];
#pragma unroll
    for (int mt = 0; mt < 4; ++mt) {
        int R0 = i0 + wm + mt * 16 + qq * 4;
#pragma unroll
        for (int nt = 0; nt < 2; ++nt) {
            int rl = wn + nt * 16 + x;
            int Ccol = j0 + rl;
            float rsum = rsLDS[0][rl] + rsLDS[1][rl];
            float linv = g / fmaxf(rsum, 1e-30f);
            float v[4];
            if (resH) {
                half4 rh = *(const half4*)(resH + ((size_t)b * PROWS + prow(Ccol)) * CC + R0);
#pragma unroll
                for (int e = 0; e < 4; ++e)
                    v[e] = acc[mt][nt][e] * linv + (float)rh[e];
            } else {
#pragma unroll
                for (int e = 0; e < 4; ++e)
                    v[e] = acc[mt][nt][e] * linv + resF[((size_t)b * CC + R0 + e) * NN + Ccol];
            }
            if (outT) {
                half4 t;
                t.x = (_Float16)v[0]; t.y = (_Float16)v[1];
                t.z = (_Float16)v[2]; t.w = (_Float16)v[3];
                *(half4*)(outT + ((size_t)b * PROWS + prow(Ccol)) * CC + R0) = t;
            }
            if (outF) {
#pragma unroll
                for (int e = 0; e < 4; ++e)
                    outF[((size_t)b * CC + R0 + e) * NN + Ccol] = v[e];
            }
        }
    }
}

// ------------------------- 3x3 conv, big tile, fused BN+ReLU -------------------------
// (exact r5 structure: 2-buffer counted-vmcnt 2-deep pipeline, flattened 72 steps)
__global__ __launch_bounds__(256) void k_conv3(const _Float16* __restrict__ Arep,
                                               const _Float16* __restrict__ Tpad,
                                               const float* __restrict__ bng,
                                               const float* __restrict__ bnb,
                                               const float* __restrict__ bnm,
                                               const float* __restrict__ bnv,
                                               float* __restrict__ outF,
                                               _Float16* __restrict__ outT) {
    __shared__ __align__(16) _Float16 As[2][128 * 64];
    __shared__ __align__(16) _Float16 Bs[2][64 * 64];
    BWAVE_IDX();
    BIG_DECODE();
    const _Float16* Tb = Tpad + (size_t)b * PROWS * CC;

    const _Float16* aBase[4]; int aOf[4];
#pragma unroll
    for (int i = 0; i < 4; ++i) {
        SLOT_A(i);
        aBase[i] = Arep + (size_t)(i0 + r) * CC + koff;
        aOf[i] = sb * 8;
    }
    const _Float16* bBase[2]; int bOf[2];
#pragma unroll
    for (int i = 0; i < 2; ++i) {
        SLOT_B(i);
        bBase[i] = Tb + (size_t)prow(j0 + r) * CC + koff;
        bOf[i] = sb * 8;
    }
    BACC_INIT();

#define STAGE_CONV(u, nb)                                                       \
    {                                                                           \
        int rt_ = (u) >> 3, ci_ = ((u) & 7) << 6;                               \
        int r3_ = rt_ / 3;                                                      \
        ptrdiff_t aoff_ = (ptrdiff_t)rt_ * (CC * CC) + ci_;                     \
        ptrdiff_t boff_ =                                                       \
            (ptrdiff_t)((r3_ - 1) * PW + (rt_ - r3_ * 3 - 1)) * CC + ci_;       \
        _Pragma("unroll") for (int i = 0; i < 4; ++i)                           \
            gl16(aBase[i] + aoff_, As[nb] + aOf[i]);                            \
        _Pragma("unroll") for (int i = 0; i < 2; ++i)                           \
            gl16(bBase[i] + boff_, Bs[nb] + bOf[i]);                            \
    }

    STAGE_CONV(0, 0);
    STAGE_CONV(1, 1);
    const int TOT = 9 * (CC / 64);   // 72
#pragma unroll 2
    for (int t = 0; t + 2 < TOT; ++t) {
        WAIT6();
        BAR();
        btile(As[t & 1], Bs[t & 1], acc, wm, wn, x, qq);
        BAR();
        STAGE_CONV(t + 2, (t & 1));
    }
    WAIT6();
    BAR();
    btile(As[(TOT - 2) & 1], Bs[(TOT - 2) & 1], acc, wm, wn, x, qq);
    WAIT0();
    BAR();
    btile(As[(TOT - 1) & 1], Bs[(TOT - 1) & 1], acc, wm, wn, x, qq);
#undef STAGE_CONV

#pragma unroll
    for (int mt = 0; mt < 4; ++mt) {
        int R0 = i0 + wm + mt * 16 + qq * 4;
        float sc[4], sh[4];
#pragma unroll
        for (int e = 0; e < 4; ++e) {
            sc[e] = bng[R0 + e] * rsqrtf(bnv[R0 + e] + 1e-5f);
            sh[e] = bnb[R0 + e] - bnm[R0 + e] * sc[e];
        }
#pragma unroll
        for (int nt = 0; nt < 2; ++nt) {
            int Ccol = j0 + wn + nt * 16 + x;
            float v[4];
#pragma unroll
            for (int e = 0; e < 4; ++e) {
                float t = acc[mt][nt][e] * sc[e] + sh[e];
                v[e] = t > 0.f ? t : 0.f;
            }
            if (outF) {
#pragma unroll
                for (int e = 0; e < 4; ++e)
                    outF[((size_t)b * CC + R0 + e) * NN + Ccol] = v[e];
            }
            half4 t4;
            t4.x = (_Float16)v[0]; t4.y = (_Float16)v[1];
            t4.z = (_Float16)v[2]; t4.w = (_Float16)v[3];
            *(half4*)(outT + ((size_t)b * PROWS + prow(Ccol)) * CC + R0) = t4;
        }
    }
}

// ---------------------------------------------------------------------------
extern "C" void kernel_launch(void* const* d_in, const int* in_sizes, int n_in,
                              void* d_out, int out_size, void* d_ws, size_t ws_size,
                              hipStream_t stream) {
    const float* xin  = (const float*)d_in[0];
    const float* Wq   = (const float*)d_in[1];
    const float* bq   = (const float*)d_in[2];
    const float* Wk   = (const float*)d_in[3];
    const float* bk   = (const float*)d_in[4];
    const float* Wv   = (const float*)d_in[5];
    const float* bv   = (const float*)d_in[6];
    const float* c1w  = (const float*)d_in[7];
    const float* bn1w = (const float*)d_in[8];
    const float* bn1b = (const float*)d_in[9];
    const float* bn1m = (const float*)d_in[10];
    const float* bn1v = (const float*)d_in[11];
    const float* c2w  = (const float*)d_in[12];
    const float* bn2w = (const float*)d_in[13];
    const float* bn2b = (const float*)d_in[14];
    const float* bn2m = (const float*)d_in[15];
    const float* bn2v = (const float*)d_in[16];
    const float* s1w  = (const float*)d_in[17];
    const float* s1b  = (const float*)d_in[18];
    const float* s2w  = (const float*)d_in[19];
    const float* s2b  = (const float*)d_in[20];
    const float* gamma  = (const float*)d_in[21];
    const float* gamma1 = (const float*)d_in[22];
    const float* gamma2 = (const float*)d_in[23];

    float* out = (float*)d_out;

    char* p = (char*)d_ws;
    _Float16* xT    = (_Float16*)p; p += (size_t)BB * NN * CC * 2;      // 9.4 MB
    _Float16* qT    = (_Float16*)p; p += (size_t)BB * NN * DDQ * 2;
    _Float16* kT    = (_Float16*)p; p += (size_t)BB * NN * DDQ * 2;
    unsigned short* vsB = (unsigned short*)p; p += (size_t)BB * CC * NN * 2;  // 9.4 MB
    _Float16* TattnP= (_Float16*)p; p += (size_t)BB * PROWS * CC * 2;   // 10.2 MB
    _Float16* TconvP= (_Float16*)p; p += (size_t)BB * PROWS * CC * 2;   // 10.2 MB
    float*    rR    = (float*)p;    p += (size_t)BB * CC * NN * 4;      // 18.9 MB
    _Float16* wq_h  = (_Float16*)p; p += (size_t)DDQ * CC * 2;
    _Float16* wk_h  = (_Float16*)p; p += (size_t)DDQ * CC * 2;
    _Float16* wv_h  = (_Float16*)p; p += (size_t)CC * CC * 2;
    _Float16* s1_h  = (_Float16*)p; p += (size_t)CC * CC * 2;
    _Float16* s2_h  = (_Float16*)p; p += (size_t)CC * CC * 2;
    _Float16* crep1 = (_Float16*)p; p += (size_t)9 * CC * CC * 2;
    _Float16* crep2 = (_Float16*)p; p += (size_t)9 * CC * CC * 2;

    dim3 blk(256);

    // zero padded activation borders
    hipMemsetAsync(TattnP, 0, (size_t)BB * PROWS * CC * 2, stream);
    hipMemsetAsync(TconvP, 0, (size_t)BB * PROWS * CC * 2, stream);

    // ---- prep ----
    k_cast_multi<<<dim3(128, 2), blk, 0, stream>>>(Wq, Wk, nullptr, wq_h, wk_h, nullptr, DDQ * CC);
    k_cast_multi<<<dim3(1024, 3), blk, 0, stream>>>(Wv, s1w, s2w, wv_h, s1_h, s2_h, CC * CC);
    k_repack_conv2<<<dim3((9 * CC * CC + 255) / 256, 2), blk, 0, stream>>>(c1w, c2w, crep1, crep2);
    k_transpose_x<<<dim3(NN / 32, CC / 32, BB), blk, 0, stream>>>(xin, xT);

    dim3 gQK(NN / 64, 2, BB);
    dim3 gBig(576);                     // 1-D, XCD-chunk swizzled in-kernel

    // projections
    k_qkproj<<<gQK, blk, 0, stream>>>(wq_h, wk_h, bq, bk, xT, qT, kT);
    k_cgemm<0, 0><<<gBig, blk, 0, stream>>>(wv_h, bv, xT, nullptr, vsB);

    // ---- stage 0: dense attention (fused) ----
    k_fattn<<<gBig, blk, 0, stream>>>(vsB, qT, kT, xin, nullptr, gamma, nullptr, TattnP, -1);
    k_conv3<<<gBig, blk, 0, stream>>>(crep1, TattnP, bn1w, bn1b, bn1m, bn1v, nullptr, TconvP);

    // ---- stage 1: radius-6 masked attention (fused) ----
    k_cgemm<1, 1><<<gBig, blk, 0, stream>>>(s1_h, s1b, TconvP, TconvP, vsB);
    k_fattn<<<gBig, blk, 0, stream>>>(vsB, qT, kT, nullptr, TconvP, gamma1, nullptr, TattnP, 6);
    k_conv3<<<gBig, blk, 0, stream>>>(crep2, TattnP, bn2w, bn2b, bn2m, bn2v, rR, TconvP);

    // ---- stage 2: radius-12 masked attention (fused) ----
    k_cgemm<1, 1><<<gBig, blk, 0, stream>>>(s2_h, s2b, TconvP, TconvP, vsB);
    k_fattn<<<gBig, blk, 0, stream>>>(vsB, qT, kT, rR, nullptr, gamma2, out, nullptr, 12);
}

// Round 10
// 460.835 us; speedup vs baseline: 1.2126x; 1.1666x over previous
//
#include <hip/hip_runtime.h>
#include <math.h>

#define BB 4
#define CC 512
#define HH 48
#define WW 48
#define NN 2304      // H*W
#define DDQ 64       // C/8
#define LDSP 72      // padded LDS stride for 64-wide tiles (fp16 elems)
#define PW 50        // padded image width (W+2)
#define PROWS 2500   // (H+2)*(W+2)

typedef __attribute__((ext_vector_type(4))) float f32x4;
typedef __attribute__((ext_vector_type(8))) _Float16 half8;
typedef __attribute__((ext_vector_type(4))) _Float16 half4;
typedef __attribute__((ext_vector_type(8))) short bf16x8;

__device__ __forceinline__ int imax(int a, int b) { return a > b ? a : b; }
__device__ __forceinline__ int imin(int a, int b) { return a < b ? a : b; }
__device__ __forceinline__ int prow(int m) {
    int h = m / WW, w = m - h * WW;
    return (h + 1) * PW + (w + 1);
}
__device__ __forceinline__ unsigned short f2bf(float f) {
    unsigned u = __float_as_uint(f);
    u += 0x7fffu + ((u >> 16) & 1u);   // RNE
    return (unsigned short)(u >> 16);
}
__device__ __forceinline__ float bf2f(unsigned short s) {
    unsigned u = ((unsigned)s) << 16;
    return __uint_as_float(u);
}

// ---- async global->LDS, 16B per lane, wave-uniform LDS base ----
typedef __attribute__((address_space(1))) unsigned int g_u32;
typedef __attribute__((address_space(3))) unsigned int l_u32;
__device__ __forceinline__ void gl16(const void* g, void* l) {
    __builtin_amdgcn_global_load_lds((const g_u32*)g, (l_u32*)l, 16, 0, 0);
}

// Counted-vmcnt pipeline fences (T3+T4): loads stay in flight across barriers.
#define WAIT6()  asm volatile("s_waitcnt vmcnt(6)" ::: "memory")
#define WAIT0()  asm volatile("s_waitcnt vmcnt(0)" ::: "memory")
#define BAR()    { __builtin_amdgcn_s_barrier(); asm volatile("" ::: "memory"); }

// XCD-chunked bijective swizzle (T1): 576 blocks, 8 XCDs, hw id raw -> XCD raw%8.
#define BIG_DECODE()                                          \
    int raw = blockIdx.x;                                     \
    int wg = ((raw & 7) * 72) + (raw >> 3);                   \
    int jx = wg % 36; int rem = wg / 36;                      \
    int j0 = jx * 64, i0 = (rem & 3) * 128, b = rem >> 2;

// ===========================================================================
// Big-tile GEMM core: 128(M) x 64(N), BK=64 elems, 256 threads, XOR swizzle.
// ===========================================================================
#define BWAVE_IDX()                                  \
    int tid = threadIdx.x;                           \
    int wave = tid >> 6, lane = tid & 63;            \
    int wm = (wave >> 1) * 64, wn = (wave & 1) * 32; \
    int x = lane & 15, qq = lane >> 4;

__device__ __forceinline__ half8 fragld(const _Float16* T, int r, int c) {
    int kb = c ^ (r & 7);
    return *(const half8*)(T + r * 64 + kb * 8);
}
__device__ __forceinline__ bf16x8 fragld_b(const unsigned short* T, int r, int c) {
    int kb = c ^ (r & 7);
    return *(const bf16x8*)(T + r * 64 + kb * 8);
}

__device__ __forceinline__ void btile(const _Float16* As, const _Float16* Bs,
                                      f32x4 acc[4][2], int wm, int wn, int x, int qq) {
#pragma unroll
    for (int ks = 0; ks < 2; ++ks) {
        int c = ks * 4 + qq;
        half8 a0 = fragld(As, wm + x, c);
        half8 a1 = fragld(As, wm + 16 + x, c);
        half8 a2 = fragld(As, wm + 32 + x, c);
        half8 a3 = fragld(As, wm + 48 + x, c);
        half8 b0 = fragld(Bs, wn + x, c);
        half8 b1 = fragld(Bs, wn + 16 + x, c);
        acc[0][0] = __builtin_amdgcn_mfma_f32_16x16x32_f16(a0, b0, acc[0][0], 0, 0, 0);
        acc[0][1] = __builtin_amdgcn_mfma_f32_16x16x32_f16(a0, b1, acc[0][1], 0, 0, 0);
        acc[1][0] = __builtin_amdgcn_mfma_f32_16x16x32_f16(a1, b0, acc[1][0], 0, 0, 0);
        acc[1][1] = __builtin_amdgcn_mfma_f32_16x16x32_f16(a1, b1, acc[1][1], 0, 0, 0);
        acc[2][0] = __builtin_amdgcn_mfma_f32_16x16x32_f16(a2, b0, acc[2][0], 0, 0, 0);
        acc[2][1] = __builtin_amdgcn_mfma_f32_16x16x32_f16(a2, b1, acc[2][1], 0, 0, 0);
        acc[3][0] = __builtin_amdgcn_mfma_f32_16x16x32_f16(a3, b0, acc[3][0], 0, 0, 0);
        acc[3][1] = __builtin_amdgcn_mfma_f32_16x16x32_f16(a3, b1, acc[3][1], 0, 0, 0);
    }
}
__device__ __forceinline__ void btile_b(const unsigned short* As, const unsigned short* Bs,
                                        f32x4 acc[4][2], int wm, int wn, int x, int qq) {
#pragma unroll
    for (int ks = 0; ks < 2; ++ks) {
        int c = ks * 4 + qq;
        bf16x8 a0 = fragld_b(As, wm + x, c);
        bf16x8 a1 = fragld_b(As, wm + 16 + x, c);
        bf16x8 a2 = fragld_b(As, wm + 32 + x, c);
        bf16x8 a3 = fragld_b(As, wm + 48 + x, c);
        bf16x8 b0 = fragld_b(Bs, wn + x, c);
        bf16x8 b1 = fragld_b(Bs, wn + 16 + x, c);
        acc[0][0] = __builtin_amdgcn_mfma_f32_16x16x32_bf16(a0, b0, acc[0][0], 0, 0, 0);
        acc[0][1] = __builtin_amdgcn_mfma_f32_16x16x32_bf16(a0, b1, acc[0][1], 0, 0, 0);
        acc[1][0] = __builtin_amdgcn_mfma_f32_16x16x32_bf16(a1, b0, acc[1][0], 0, 0, 0);
        acc[1][1] = __builtin_amdgcn_mfma_f32_16x16x32_bf16(a1, b1, acc[1][1], 0, 0, 0);
        acc[2][0] = __builtin_amdgcn_mfma_f32_16x16x32_bf16(a2, b0, acc[2][0], 0, 0, 0);
        acc[2][1] = __builtin_amdgcn_mfma_f32_16x16x32_bf16(a2, b1, acc[2][1], 0, 0, 0);
        acc[3][0] = __builtin_amdgcn_mfma_f32_16x16x32_bf16(a3, b0, acc[3][0], 0, 0, 0);
        acc[3][1] = __builtin_amdgcn_mfma_f32_16x16x32_bf16(a3, b1, acc[3][1], 0, 0, 0);
    }
}

#define BACC_INIT()                                         \
    f32x4 zf = {0.f, 0.f, 0.f, 0.f};                        \
    f32x4 acc[4][2];                                        \
    _Pragma("unroll") for (int i_ = 0; i_ < 4; ++i_) {      \
        acc[i_][0] = zf; acc[i_][1] = zf; }

#define SLOT_A(i) int sb = (wave * 4 + (i)) * 64; int s = sb + lane; \
                  int r = s >> 3, kb = s & 7; int koff = ((kb ^ (r & 7)) << 3);
#define SLOT_B(i) int sb = (wave * 2 + (i)) * 64; int s = sb + lane; \
                  int r = s >> 3, kb = s & 7; int koff = ((kb ^ (r & 7)) << 3);

// ===========================================================================
// small 64^2 helpers
// ===========================================================================
__device__ __forceinline__ void stage_rows(_Float16* dst, const _Float16* __restrict__ src,
                                           int ld, int row0, int k0, int tid) {
#pragma unroll
    for (int i = 0; i < 2; ++i) {
        int s = tid * 2 + i;
        int r = s >> 3, off = (s & 7) << 3;
        *(half8*)(dst + r * LDSP + off) =
            *(const half8*)(src + (size_t)(row0 + r) * ld + k0 + off);
    }
}
__device__ __forceinline__ void mfma_tile(const _Float16* As, const _Float16* Bs,
                                          f32x4 acc[2][2], int wm, int wn, int x, int qq) {
#pragma unroll
    for (int ks = 0; ks < 2; ++ks) {
        int kof = ks * 32 + qq * 8;
        half8 a0 = *(const half8*)(As + (wm + x) * LDSP + kof);
        half8 a1 = *(const half8*)(As + (wm + 16 + x) * LDSP + kof);
        half8 b0 = *(const half8*)(Bs + (wn + x) * LDSP + kof);
        half8 b1 = *(const half8*)(Bs + (wn + 16 + x) * LDSP + kof);
        acc[0][0] = __builtin_amdgcn_mfma_f32_16x16x32_f16(a0, b0, acc[0][0], 0, 0, 0);
        acc[0][1] = __builtin_amdgcn_mfma_f32_16x16x32_f16(a0, b1, acc[0][1], 0, 0, 0);
        acc[1][0] = __builtin_amdgcn_mfma_f32_16x16x32_f16(a1, b0, acc[1][0], 0, 0, 0);
        acc[1][1] = __builtin_amdgcn_mfma_f32_16x16x32_f16(a1, b1, acc[1][1], 0, 0, 0);
    }
}
#define WAVE_IDX()                             \
    int tid = threadIdx.x;                     \
    int wave = tid >> 6, lane = tid & 63;      \
    int wm = (wave >> 1) * 32, wn = (wave & 1) * 32; \
    int x = lane & 15, qq = lane >> 4;
#define ACC_INIT()                             \
    f32x4 zf = {0.f, 0.f, 0.f, 0.f};           \
    f32x4 acc[2][2];                           \
    acc[0][0] = zf; acc[0][1] = zf; acc[1][0] = zf; acc[1][1] = zf;

// ------------------------- prep kernels -------------------------
__global__ __launch_bounds__(256) void k_cast_multi(const float* __restrict__ s0,
                                                    const float* __restrict__ s1,
                                                    const float* __restrict__ s2,
                                                    _Float16* __restrict__ d0,
                                                    _Float16* __restrict__ d1,
                                                    _Float16* __restrict__ d2, int n) {
    const float* s = blockIdx.y == 0 ? s0 : (blockIdx.y == 1 ? s1 : s2);
    _Float16* d = blockIdx.y == 0 ? d0 : (blockIdx.y == 1 ? d1 : d2);
    for (int i = blockIdx.x * 256 + threadIdx.x; i < n; i += gridDim.x * 256)
        d[i] = (_Float16)s[i];
}

// zero only the BORDER cells of the padded activation buffers (interior is
// fully overwritten by k_attn/k_conv3 before any read). 196 border cells.
__global__ __launch_bounds__(256) void k_zero_border(_Float16* __restrict__ p0,
                                                     _Float16* __restrict__ p1) {
    int idx = blockIdx.x;        // 0..195
    int b = blockIdx.z;
    _Float16* dst = blockIdx.y ? p1 : p0;
    int h, w;
    if (idx < 50)       { h = 0;  w = idx; }
    else if (idx < 100) { h = 49; w = idx - 50; }
    else if (idx < 148) { h = idx - 100 + 1; w = 0; }
    else                { h = idx - 148 + 1; w = 49; }
    int pr = h * PW + w;
    // 512 fp16 channels = 1 KB; 256 threads x 1 uint
    unsigned* q = (unsigned*)(dst + ((size_t)b * PROWS + pr) * CC);
    q[threadIdx.x] = 0u;
}

__global__ __launch_bounds__(256) void k_repack_conv2(const float* __restrict__ w1,
                                                      const float* __restrict__ w2,
                                                      _Float16* __restrict__ d1,
                                                      _Float16* __restrict__ d2) {
    const float* w = blockIdx.y ? w2 : w1;
    _Float16* dst = blockIdx.y ? d2 : d1;
    int i = blockIdx.x * 256 + threadIdx.x;
    if (i >= 9 * CC * CC) return;
    int r = i / (CC * CC);
    int rem = i - r * CC * CC;
    int co = rem / CC, ci = rem - (rem / CC) * CC;
    dst[i] = (_Float16)w[((size_t)co * CC + ci) * 9 + r];
}

__global__ __launch_bounds__(256) void k_transpose_x(const float* __restrict__ x,
                                                     _Float16* __restrict__ xT) {
    __shared__ float tile[32][33];
    int b = blockIdx.z;
    int c0 = blockIdx.y * 32, n0 = blockIdx.x * 32;
    int tx = threadIdx.x & 31, ty = threadIdx.x >> 5;
    const float* xb = x + (size_t)b * CC * NN;
#pragma unroll
    for (int rr = 0; rr < 32; rr += 8)
        tile[ty + rr][tx] = xb[(size_t)(c0 + ty + rr) * NN + n0 + tx];
    __syncthreads();
    _Float16* xTb = xT + (size_t)b * NN * CC;
#pragma unroll
    for (int rr = 0; rr < 32; rr += 8)
        xTb[(size_t)(n0 + ty + rr) * CC + c0 + tx] = (_Float16)tile[tx][ty + rr];
}

// ------------------------- q/k projection -------------------------
__global__ __launch_bounds__(256) void k_qkproj(const _Float16* __restrict__ Wq,
                                                const _Float16* __restrict__ Wk,
                                                const float* __restrict__ bq,
                                                const float* __restrict__ bk,
                                                const _Float16* __restrict__ xT,
                                                _Float16* __restrict__ qT,
                                                _Float16* __restrict__ kT) {
    __shared__ _Float16 As[64 * LDSP];
    __shared__ _Float16 Bs[64 * LDSP];
    WAVE_IDX();
    int j0 = blockIdx.x * 64, b = blockIdx.z;
    const _Float16* Wp = blockIdx.y ? Wk : Wq;
    const float* bias = blockIdx.y ? bk : bq;
    _Float16* outT = blockIdx.y ? kT : qT;
    const _Float16* xTb = xT + (size_t)b * NN * CC;
    ACC_INIT();
    for (int kc = 0; kc < CC; kc += 64) {
        stage_rows(As, Wp, CC, 0, kc, tid);
        stage_rows(Bs, xTb, CC, j0, kc, tid);
        __syncthreads();
        mfma_tile(As, Bs, acc, wm, wn, x, qq);
        __syncthreads();
    }
#pragma unroll
    for (int ms = 0; ms < 2; ++ms) {
        int R0 = wm + ms * 16 + qq * 4;
#pragma unroll
        for (int ns = 0; ns < 2; ++ns) {
            int Ccol = j0 + wn + ns * 16 + x;
            half4 t;
            t.x = (_Float16)(acc[ms][ns][0] + bias[R0 + 0]);
            t.y = (_Float16)(acc[ms][ns][1] + bias[R0 + 1]);
            t.z = (_Float16)(acc[ms][ns][2] + bias[R0 + 2]);
            t.w = (_Float16)(acc[ms][ns][3] + bias[R0 + 3]);
            *(half4*)(outT + ((size_t)b * NN + Ccol) * DDQ + R0) = t;
        }
    }
}

// ------------------------- C x C GEMM, big tile (out: bf16) -------------------------
// 2-buffer counted-vmcnt 2-deep pipeline + XCD chunking. Gate read as fp16.
template <int EPI, int PAD>
__global__ __launch_bounds__(256) void k_cgemm(const _Float16* __restrict__ W,
                                               const float* __restrict__ bias,
                                               const _Float16* __restrict__ Bsrc,
                                               const _Float16* __restrict__ gateH,
                                               unsigned short* __restrict__ out) {
    __shared__ __align__(16) _Float16 As[2][128 * 64];
    __shared__ __align__(16) _Float16 Bs[2][64 * 64];
    BWAVE_IDX();
    BIG_DECODE();
    const _Float16* Bb = Bsrc + (size_t)b * (PAD ? (size_t)PROWS * CC : (size_t)NN * CC);

    const _Float16* aSrc[4]; int aOf[4];
#pragma unroll
    for (int i = 0; i < 4; ++i) {
        SLOT_A(i);
        aSrc[i] = W + (size_t)(i0 + r) * CC + koff;
        aOf[i] = sb * 8;
    }
    const _Float16* bSrc[2]; int bOf[2];
#pragma unroll
    for (int i = 0; i < 2; ++i) {
        SLOT_B(i);
        int row = PAD ? prow(j0 + r) : (j0 + r);
        bSrc[i] = Bb + (size_t)row * CC + koff;
        bOf[i] = sb * 8;
    }
    BACC_INIT();
#define STG_G(kc, nb)                                                          \
    { _Pragma("unroll") for (int i = 0; i < 4; ++i)                            \
          gl16(aSrc[i] + (kc), As[nb] + aOf[i]);                               \
      _Pragma("unroll") for (int i = 0; i < 2; ++i)                            \
          gl16(bSrc[i] + (kc), Bs[nb] + bOf[i]); }
    STG_G(0, 0);
    STG_G(64, 1);
    const int NSTEP = CC / 64;   // 8
#pragma unroll
    for (int t = 0; t + 2 < NSTEP; ++t) {   // t = 0..5
        WAIT6();
        BAR();
        btile(As[t & 1], Bs[t & 1], acc, wm, wn, x, qq);
        BAR();
        STG_G((t + 2) * 64, (t & 1));
    }
    WAIT6();
    BAR();
    btile(As[(NSTEP - 2) & 1], Bs[(NSTEP - 2) & 1], acc, wm, wn, x, qq);
    WAIT0();
    BAR();
    btile(As[(NSTEP - 1) & 1], Bs[(NSTEP - 1) & 1], acc, wm, wn, x, qq);
#undef STG_G
#pragma unroll
    for (int mt = 0; mt < 4; ++mt) {
        int R0 = i0 + wm + mt * 16 + qq * 4;
#pragma unroll
        for (int nt = 0; nt < 2; ++nt) {
            int Ccol = j0 + wn + nt * 16 + x;
            half4 gh;
            if (EPI == 1)
                gh = *(const half4*)(gateH + ((size_t)b * PROWS + prow(Ccol)) * CC + R0);
#pragma unroll
            for (int e = 0; e < 4; ++e) {
                float v = acc[mt][nt][e] + bias[R0 + e];
                size_t idx = ((size_t)b * CC + R0 + e) * NN + Ccol;
                if (EPI == 1) v = (float)gh[e] / (1.f + __expf(-v));
                out[idx] = f2bf(v);
            }
        }
    }
}

// ------------------------- energy -> exp -> bf16 + row sums -------------------------
__global__ __launch_bounds__(256) void k_exp(const _Float16* __restrict__ qT,
                                             const _Float16* __restrict__ kT,
                                             unsigned short* __restrict__ attnB,
                                             float* __restrict__ rowsum, int rad) {
    __shared__ _Float16 qs[64 * LDSP];
    __shared__ _Float16 ks[64 * LDSP];
    __shared__ unsigned short Eh[64 * 72];
    __shared__ float psum[512];
    WAVE_IDX();
    int j0 = blockIdx.x * 64, i0 = blockIdx.y * 64, b = blockIdx.z;
    if (rad > 0) {
        int hlo = i0 / WW, hhi = (i0 + 63) / WW;
        int h2lo = imax(0, hlo - rad), h2hi = imin(HH - 1, hhi + rad);
        int klo = (h2lo * WW) & ~63;
        int khi = imin(NN, ((h2hi + 1) * WW + 63) & ~63);
        if (j0 + 64 <= klo || j0 >= khi) return;
    }
    stage_rows(qs, qT + (size_t)b * NN * DDQ, DDQ, i0, 0, tid);
    stage_rows(ks, kT + (size_t)b * NN * DDQ, DDQ, j0, 0, tid);
    __syncthreads();
    ACC_INIT();
    mfma_tile(qs, ks, acc, wm, wn, x, qq);
#pragma unroll
    for (int ns = 0; ns < 2; ++ns) {
        int col = wn + ns * 16 + x;
        int gn = j0 + col;
        int hn = gn / WW, cn = gn % WW;
#pragma unroll
        for (int ms = 0; ms < 2; ++ms)
#pragma unroll
            for (int e = 0; e < 4; ++e) {
                int row = wm + ms * 16 + qq * 4 + e;
                int gm = i0 + row;
                bool valid = true;
                if (rad > 0) {
                    int dh = gm / WW - hn; if (dh < 0) dh = -dh;
                    int dc = gm % WW - cn; if (dc < 0) dc = -dc;
                    valid = (dh <= rad) && (dc <= rad);
                }
                float w = valid ? __expf(acc[ms][ns][e]) : 0.f;
                Eh[row * 72 + col] = f2bf(w);
            }
    }
    __syncthreads();
#pragma unroll
    for (int t = 0; t < 2; ++t) {
        int s = tid + t * 256;
        int r = s >> 3, cg = (s & 7) << 3;
        bf16x8 v = *(const bf16x8*)(Eh + r * 72 + cg);
        *(bf16x8*)(attnB + ((size_t)b * NN + i0 + r) * NN + j0 + cg) = v;
        float ss = 0.f;
#pragma unroll
        for (int j = 0; j < 8; ++j) ss += bf2f((unsigned short)v[j]);
        psum[s] = ss;
    }
    __syncthreads();
    if (tid < 64) {
        float tot = 0.f;
#pragma unroll
        for (int g = 0; g < 8; ++g) tot += psum[tid * 8 + g];
        atomicAdd(rowsum + (size_t)b * NN + i0 + tid, tot);
    }
}

// ------------------------- attention apply, big tile, bf16 -------------------------
// 2-buffer counted-vmcnt 2-deep pipeline + XCD chunking.
__global__ __launch_bounds__(256) void k_attn(const unsigned short* __restrict__ A,
                                              const unsigned short* __restrict__ attnB,
                                              const float* __restrict__ rowsum,
                                              const float* __restrict__ resF,
                                              const _Float16* __restrict__ resH,
                                              const float* __restrict__ gamma,
                                              float* __restrict__ outF,
                                              _Float16* __restrict__ outT, int rad) {
    __shared__ __align__(16) unsigned short As[2][128 * 64];
    __shared__ __align__(16) unsigned short Bs[2][64 * 64];
    BWAVE_IDX();
    BIG_DECODE();
    int klo = 0, khi = NN;
    if (rad > 0) {
        int hlo = j0 / WW, hhi = (j0 + 63) / WW;
        int h2lo = imax(0, hlo - rad), h2hi = imin(HH - 1, hhi + rad);
        klo = (h2lo * WW) & ~63;
        khi = imin(NN, ((h2hi + 1) * WW + 63) & ~63);
    }
    const unsigned short* Ab = A + (size_t)b * CC * NN;
    const unsigned short* Tb = attnB + (size_t)b * NN * NN;

    const unsigned short* aSrc[4]; int aOf[4];
#pragma unroll
    for (int i = 0; i < 4; ++i) {
        SLOT_A(i);
        aSrc[i] = Ab + (size_t)(i0 + r) * NN + koff + klo;
        aOf[i] = sb * 8;
    }
    const unsigned short* bSrc[2]; int bOf[2];
#pragma unroll
    for (int i = 0; i < 2; ++i) {
        SLOT_B(i);
        bSrc[i] = Tb + (size_t)(j0 + r) * NN + koff + klo;
        bOf[i] = sb * 8;
    }
    BACC_INIT();
    int nsteps = (khi - klo) >> 6;
#define STG_T(kc, nb)                                                          \
    { _Pragma("unroll") for (int i = 0; i < 4; ++i)                            \
          gl16(aSrc[i] + (kc), As[nb] + aOf[i]);                               \
      _Pragma("unroll") for (int i = 0; i < 2; ++i)                            \
          gl16(bSrc[i] + (kc), Bs[nb] + bOf[i]); }
    STG_T(0, 0);
    STG_T(64, 1);
    for (int t = 0; t + 2 < nsteps; ++t) {
        WAIT6();
        BAR();
        btile_b(As[t & 1], Bs[t & 1], acc, wm, wn, x, qq);
        BAR();
        STG_T((t + 2) << 6, (t & 1));
    }
    WAIT6();
    BAR();
    btile_b(As[(nsteps - 2) & 1], Bs[(nsteps - 2) & 1], acc, wm, wn, x, qq);
    WAIT0();
    BAR();
    btile_b(As[(nsteps - 1) & 1], Bs[(nsteps - 1) & 1], acc, wm, wn, x, qq);
#undef STG_T
    float g = gamma[0];
#pragma unroll
    for (int mt = 0; mt < 4; ++mt) {
        int R0 = i0 + wm + mt * 16 + qq * 4;
#pragma unroll
        for (int nt = 0; nt < 2; ++nt) {
            int Ccol = j0 + wn + nt * 16 + x;
            float linv = g / fmaxf(rowsum[(size_t)b * NN + Ccol], 1e-30f);
            float v[4];
            if (resH) {
                half4 rh = *(const half4*)(resH + ((size_t)b * PROWS + prow(Ccol)) * CC + R0);
#pragma unroll
                for (int e = 0; e < 4; ++e)
                    v[e] = acc[mt][nt][e] * linv + (float)rh[e];
            } else {
#pragma unroll
                for (int e = 0; e < 4; ++e)
                    v[e] = acc[mt][nt][e] * linv + resF[((size_t)b * CC + R0 + e) * NN + Ccol];
            }
            if (outT) {
                half4 t;
                t.x = (_Float16)v[0]; t.y = (_Float16)v[1];
                t.z = (_Float16)v[2]; t.w = (_Float16)v[3];
                *(half4*)(outT + ((size_t)b * PROWS + prow(Ccol)) * CC + R0) = t;
            }
            if (outF) {
#pragma unroll
                for (int e = 0; e < 4; ++e)
                    outF[((size_t)b * CC + R0 + e) * NN + Ccol] = v[e];
            }
        }
    }
}

// ------------------------- 3x3 conv, big tile, fused BN+ReLU -------------------------
// 2-buffer counted-vmcnt 2-deep pipeline over flattened 72 (tap x kc) steps.
__global__ __launch_bounds__(256) void k_conv3(const _Float16* __restrict__ Arep,
                                               const _Float16* __restrict__ Tpad,
                                               const float* __restrict__ bng,
                                               const float* __restrict__ bnb,
                                               const float* __restrict__ bnm,
                                               const float* __restrict__ bnv,
                                               float* __restrict__ outF,
                                               _Float16* __restrict__ outT) {
    __shared__ __align__(16) _Float16 As[2][128 * 64];
    __shared__ __align__(16) _Float16 Bs[2][64 * 64];
    BWAVE_IDX();
    BIG_DECODE();
    const _Float16* Tb = Tpad + (size_t)b * PROWS * CC;

    const _Float16* aBase[4]; int aOf[4];
#pragma unroll
    for (int i = 0; i < 4; ++i) {
        SLOT_A(i);
        aBase[i] = Arep + (size_t)(i0 + r) * CC + koff;
        aOf[i] = sb * 8;
    }
    const _Float16* bBase[2]; int bOf[2];
#pragma unroll
    for (int i = 0; i < 2; ++i) {
        SLOT_B(i);
        bBase[i] = Tb + (size_t)prow(j0 + r) * CC + koff;
        bOf[i] = sb * 8;
    }
    BACC_INIT();

#define STAGE_CONV(u, nb)                                                       \
    {                                                                           \
        int rt_ = (u) >> 3, ci_ = ((u) & 7) << 6;                               \
        int r3_ = rt_ / 3;                                                      \
        ptrdiff_t aoff_ = (ptrdiff_t)rt_ * (CC * CC) + ci_;                     \
        ptrdiff_t boff_ =                                                       \
            (ptrdiff_t)((r3_ - 1) * PW + (rt_ - r3_ * 3 - 1)) * CC + ci_;       \
        _Pragma("unroll") for (int i = 0; i < 4; ++i)                           \
            gl16(aBase[i] + aoff_, As[nb] + aOf[i]);                            \
        _Pragma("unroll") for (int i = 0; i < 2; ++i)                           \
            gl16(bBase[i] + boff_, Bs[nb] + bOf[i]);                            \
    }

    STAGE_CONV(0, 0);
    STAGE_CONV(1, 1);
    const int TOT = 9 * (CC / 64);   // 72
#pragma unroll 2
    for (int t = 0; t + 2 < TOT; ++t) {
        WAIT6();
        BAR();
        btile(As[t & 1], Bs[t & 1], acc, wm, wn, x, qq);
        BAR();
        STAGE_CONV(t + 2, (t & 1));
    }
    WAIT6();
    BAR();
    btile(As[(TOT - 2) & 1], Bs[(TOT - 2) & 1], acc, wm, wn, x, qq);
    WAIT0();
    BAR();
    btile(As[(TOT - 1) & 1], Bs[(TOT - 1) & 1], acc, wm, wn, x, qq);
#undef STAGE_CONV

#pragma unroll
    for (int mt = 0; mt < 4; ++mt) {
        int R0 = i0 + wm + mt * 16 + qq * 4;
        float sc[4], sh[4];
#pragma unroll
        for (int e = 0; e < 4; ++e) {
            sc[e] = bng[R0 + e] * rsqrtf(bnv[R0 + e] + 1e-5f);
            sh[e] = bnb[R0 + e] - bnm[R0 + e] * sc[e];
        }
#pragma unroll
        for (int nt = 0; nt < 2; ++nt) {
            int Ccol = j0 + wn + nt * 16 + x;
            float v[4];
#pragma unroll
            for (int e = 0; e < 4; ++e) {
                float t = acc[mt][nt][e] * sc[e] + sh[e];
                v[e] = t > 0.f ? t : 0.f;
            }
            if (outF) {
#pragma unroll
                for (int e = 0; e < 4; ++e)
                    outF[((size_t)b * CC + R0 + e) * NN + Ccol] = v[e];
            }
            half4 t4;
            t4.x = (_Float16)v[0]; t4.y = (_Float16)v[1];
            t4.z = (_Float16)v[2]; t4.w = (_Float16)v[3];
            *(half4*)(outT + ((size_t)b * PROWS + prow(Ccol)) * CC + R0) = t4;
        }
    }
}

// ---------------------------------------------------------------------------
extern "C" void kernel_launch(void* const* d_in, const int* in_sizes, int n_in,
                              void* d_out, int out_size, void* d_ws, size_t ws_size,
                              hipStream_t stream) {
    const float* xin  = (const float*)d_in[0];
    const float* Wq   = (const float*)d_in[1];
    const float* bq   = (const float*)d_in[2];
    const float* Wk   = (const float*)d_in[3];
    const float* bk   = (const float*)d_in[4];
    const float* Wv   = (const float*)d_in[5];
    const float* bv   = (const float*)d_in[6];
    const float* c1w  = (const float*)d_in[7];
    const float* bn1w = (const float*)d_in[8];
    const float* bn1b = (const float*)d_in[9];
    const float* bn1m = (const float*)d_in[10];
    const float* bn1v = (const float*)d_in[11];
    const float* c2w  = (const float*)d_in[12];
    const float* bn2w = (const float*)d_in[13];
    const float* bn2b = (const float*)d_in[14];
    const float* bn2m = (const float*)d_in[15];
    const float* bn2v = (const float*)d_in[16];
    const float* s1w  = (const float*)d_in[17];
    const float* s1b  = (const float*)d_in[18];
    const float* s2w  = (const float*)d_in[19];
    const float* s2b  = (const float*)d_in[20];
    const float* gamma  = (const float*)d_in[21];
    const float* gamma1 = (const float*)d_in[22];
    const float* gamma2 = (const float*)d_in[23];

    float* out = (float*)d_out;

    char* p = (char*)d_ws;
    unsigned short* attn = (unsigned short*)p; p += (size_t)BB * NN * NN * 2;  // 42.5 MB
    _Float16* xT    = (_Float16*)p; p += (size_t)BB * NN * CC * 2;      // 9.4 MB
    _Float16* qT    = (_Float16*)p; p += (size_t)BB * NN * DDQ * 2;
    _Float16* kT    = (_Float16*)p; p += (size_t)BB * NN * DDQ * 2;
    unsigned short* vsB = (unsigned short*)p; p += (size_t)BB * CC * NN * 2;  // 9.4 MB
    _Float16* TattnP= (_Float16*)p; p += (size_t)BB * PROWS * CC * 2;   // 10.2 MB
    _Float16* TconvP= (_Float16*)p; p += (size_t)BB * PROWS * CC * 2;   // 10.2 MB
    float*    rR    = (float*)p;    p += (size_t)BB * CC * NN * 4;      // 18.9 MB
    _Float16* wq_h  = (_Float16*)p; p += (size_t)DDQ * CC * 2;
    _Float16* wk_h  = (_Float16*)p; p += (size_t)DDQ * CC * 2;
    _Float16* wv_h  = (_Float16*)p; p += (size_t)CC * CC * 2;
    _Float16* s1_h  = (_Float16*)p; p += (size_t)CC * CC * 2;
    _Float16* s2_h  = (_Float16*)p; p += (size_t)CC * CC * 2;
    _Float16* crep1 = (_Float16*)p; p += (size_t)9 * CC * CC * 2;
    _Float16* crep2 = (_Float16*)p; p += (size_t)9 * CC * CC * 2;
    float*    rowsum= (float*)p;    p += (size_t)3 * BB * NN * 4;       // 110 KB (3 stages)

    dim3 blk(256);

    // zero rowsums (small) + only BORDER cells of the padded buffers
    hipMemsetAsync(rowsum, 0, (size_t)3 * BB * NN * 4, stream);
    k_zero_border<<<dim3(196, 2, BB), blk, 0, stream>>>(TattnP, TconvP);

    // ---- prep ----
    k_cast_multi<<<dim3(128, 2), blk, 0, stream>>>(Wq, Wk, nullptr, wq_h, wk_h, nullptr, DDQ * CC);
    k_cast_multi<<<dim3(1024, 3), blk, 0, stream>>>(Wv, s1w, s2w, wv_h, s1_h, s2_h, CC * CC);
    k_repack_conv2<<<dim3((9 * CC * CC + 255) / 256, 2), blk, 0, stream>>>(c1w, c2w, crep1, crep2);
    k_transpose_x<<<dim3(NN / 32, CC / 32, BB), blk, 0, stream>>>(xin, xT);

    dim3 gQK(NN / 64, 2, BB);
    dim3 gExp(NN / 64, NN / 64, BB);    // (36, 36, 4) = 5184 blocks
    dim3 gBig(576);                     // 1-D, XCD-chunk swizzled in-kernel

    float* rs0 = rowsum;
    float* rs1 = rowsum + (size_t)BB * NN;
    float* rs2 = rowsum + (size_t)2 * BB * NN;

    // projections
    k_qkproj<<<gQK, blk, 0, stream>>>(wq_h, wk_h, bq, bk, xT, qT, kT);
    k_cgemm<0, 0><<<gBig, blk, 0, stream>>>(wv_h, bv, xT, nullptr, vsB);

    // ---- stage 0: dense attention ----
    k_exp<<<gExp, blk, 0, stream>>>(qT, kT, attn, rs0, -1);
    k_attn<<<gBig, blk, 0, stream>>>(vsB, attn, rs0, xin, nullptr, gamma, nullptr, TattnP, -1);
    k_conv3<<<gBig, blk, 0, stream>>>(crep1, TattnP, bn1w, bn1b, bn1m, bn1v, nullptr, TconvP);

    // ---- stage 1: radius-6 masked attention ----
    k_cgemm<1, 1><<<gBig, blk, 0, stream>>>(s1_h, s1b, TconvP, TconvP, vsB);
    k_exp<<<gExp, blk, 0, stream>>>(qT, kT, attn, rs1, 6);
    k_attn<<<gBig, blk, 0, stream>>>(vsB, attn, rs1, nullptr, TconvP, gamma1, nullptr, TattnP, 6);
    k_conv3<<<gBig, blk, 0, stream>>>(crep2, TattnP, bn2w, bn2b, bn2m, bn2v, rR, TconvP);

    // ---- stage 2: radius-12 masked attention ----
    k_cgemm<1, 1><<<gBig, blk, 0, stream>>>(s2_h, s2b, TconvP, TconvP, vsB);
    k_exp<<<gExp, blk, 0, stream>>>(qT, kT, attn, rs2, 12);
    k_attn<<<gBig, blk, 0, stream>>>(vsB, attn, rs2, rR, nullptr, gamma2, out, nullptr, 12);
}

// Round 11
// 452.245 us; speedup vs baseline: 1.2356x; 1.0190x over previous
//
#include <hip/hip_runtime.h>
#include <math.h>

#define BB 4
#define CC 512
#define HH 48
#define WW 48
#define NN 2304      // H*W
#define DDQ 64       // C/8
#define LDSP 72      // padded LDS stride for 64-wide tiles (fp16 elems)
#define PW 50        // padded image width (W+2)
#define PROWS 2500   // (H+2)*(W+2)

typedef __attribute__((ext_vector_type(4))) float f32x4;
typedef __attribute__((ext_vector_type(8))) _Float16 half8;
typedef __attribute__((ext_vector_type(4))) _Float16 half4;
typedef __attribute__((ext_vector_type(8))) short bf16x8;

__device__ __forceinline__ int imax(int a, int b) { return a > b ? a : b; }
__device__ __forceinline__ int imin(int a, int b) { return a < b ? a : b; }
__device__ __forceinline__ int prow(int m) {
    int h = m / WW, w = m - h * WW;
    return (h + 1) * PW + (w + 1);
}
__device__ __forceinline__ unsigned short f2bf(float f) {
    unsigned u = __float_as_uint(f);
    u += 0x7fffu + ((u >> 16) & 1u);   // RNE
    return (unsigned short)(u >> 16);
}
__device__ __forceinline__ float bf2f(unsigned short s) {
    unsigned u = ((unsigned)s) << 16;
    return __uint_as_float(u);
}

// ---- async global->LDS, 16B per lane, wave-uniform LDS base ----
typedef __attribute__((address_space(1))) unsigned int g_u32;
typedef __attribute__((address_space(3))) unsigned int l_u32;
__device__ __forceinline__ void gl16(const void* g, void* l) {
    __builtin_amdgcn_global_load_lds((const g_u32*)g, (l_u32*)l, 16, 0, 0);
}

// Counted-vmcnt pipeline fences (T3+T4): loads stay in flight across barriers.
#define WAIT6()  asm volatile("s_waitcnt vmcnt(6)" ::: "memory")
#define WAIT0()  asm volatile("s_waitcnt vmcnt(0)" ::: "memory")
#define BAR()    { __builtin_amdgcn_s_barrier(); asm volatile("" ::: "memory"); }

// XCD-chunked bijective swizzle (T1): 576 blocks, 8 XCDs, hw id raw -> XCD raw%8.
// wg = (raw%8)*72 + raw/8 gives each XCD a contiguous chunk of 72 logical blocks
// = 2 (i0,b) operand slabs x 36 j0 -> A slab + B slab fit the 4MB per-XCD L2.
#define BIG_DECODE()                                          \
    int raw = blockIdx.x;                                     \
    int wg = ((raw & 7) * 72) + (raw >> 3);                   \
    int jx = wg % 36; int rem = wg / 36;                      \
    int j0 = jx * 64, i0 = (rem & 3) * 128, b = rem >> 2;

// ===========================================================================
// Big-tile GEMM core: 128(M) x 64(N), BK=64 elems, 256 threads, XOR swizzle.
// ===========================================================================
#define BWAVE_IDX()                                  \
    int tid = threadIdx.x;                           \
    int wave = tid >> 6, lane = tid & 63;            \
    int wm = (wave >> 1) * 64, wn = (wave & 1) * 32; \
    int x = lane & 15, qq = lane >> 4;

__device__ __forceinline__ half8 fragld(const _Float16* T, int r, int c) {
    int kb = c ^ (r & 7);
    return *(const half8*)(T + r * 64 + kb * 8);
}
__device__ __forceinline__ bf16x8 fragld_b(const unsigned short* T, int r, int c) {
    int kb = c ^ (r & 7);
    return *(const bf16x8*)(T + r * 64 + kb * 8);
}

__device__ __forceinline__ void btile(const _Float16* As, const _Float16* Bs,
                                      f32x4 acc[4][2], int wm, int wn, int x, int qq) {
#pragma unroll
    for (int ks = 0; ks < 2; ++ks) {
        int c = ks * 4 + qq;
        half8 a0 = fragld(As, wm + x, c);
        half8 a1 = fragld(As, wm + 16 + x, c);
        half8 a2 = fragld(As, wm + 32 + x, c);
        half8 a3 = fragld(As, wm + 48 + x, c);
        half8 b0 = fragld(Bs, wn + x, c);
        half8 b1 = fragld(Bs, wn + 16 + x, c);
        acc[0][0] = __builtin_amdgcn_mfma_f32_16x16x32_f16(a0, b0, acc[0][0], 0, 0, 0);
        acc[0][1] = __builtin_amdgcn_mfma_f32_16x16x32_f16(a0, b1, acc[0][1], 0, 0, 0);
        acc[1][0] = __builtin_amdgcn_mfma_f32_16x16x32_f16(a1, b0, acc[1][0], 0, 0, 0);
        acc[1][1] = __builtin_amdgcn_mfma_f32_16x16x32_f16(a1, b1, acc[1][1], 0, 0, 0);
        acc[2][0] = __builtin_amdgcn_mfma_f32_16x16x32_f16(a2, b0, acc[2][0], 0, 0, 0);
        acc[2][1] = __builtin_amdgcn_mfma_f32_16x16x32_f16(a2, b1, acc[2][1], 0, 0, 0);
        acc[3][0] = __builtin_amdgcn_mfma_f32_16x16x32_f16(a3, b0, acc[3][0], 0, 0, 0);
        acc[3][1] = __builtin_amdgcn_mfma_f32_16x16x32_f16(a3, b1, acc[3][1], 0, 0, 0);
    }
}
__device__ __forceinline__ void btile_b(const unsigned short* As, const unsigned short* Bs,
                                        f32x4 acc[4][2], int wm, int wn, int x, int qq) {
#pragma unroll
    for (int ks = 0; ks < 2; ++ks) {
        int c = ks * 4 + qq;
        bf16x8 a0 = fragld_b(As, wm + x, c);
        bf16x8 a1 = fragld_b(As, wm + 16 + x, c);
        bf16x8 a2 = fragld_b(As, wm + 32 + x, c);
        bf16x8 a3 = fragld_b(As, wm + 48 + x, c);
        bf16x8 b0 = fragld_b(Bs, wn + x, c);
        bf16x8 b1 = fragld_b(Bs, wn + 16 + x, c);
        acc[0][0] = __builtin_amdgcn_mfma_f32_16x16x32_bf16(a0, b0, acc[0][0], 0, 0, 0);
        acc[0][1] = __builtin_amdgcn_mfma_f32_16x16x32_bf16(a0, b1, acc[0][1], 0, 0, 0);
        acc[1][0] = __builtin_amdgcn_mfma_f32_16x16x32_bf16(a1, b0, acc[1][0], 0, 0, 0);
        acc[1][1] = __builtin_amdgcn_mfma_f32_16x16x32_bf16(a1, b1, acc[1][1], 0, 0, 0);
        acc[2][0] = __builtin_amdgcn_mfma_f32_16x16x32_bf16(a2, b0, acc[2][0], 0, 0, 0);
        acc[2][1] = __builtin_amdgcn_mfma_f32_16x16x32_bf16(a2, b1, acc[2][1], 0, 0, 0);
        acc[3][0] = __builtin_amdgcn_mfma_f32_16x16x32_bf16(a3, b0, acc[3][0], 0, 0, 0);
        acc[3][1] = __builtin_amdgcn_mfma_f32_16x16x32_bf16(a3, b1, acc[3][1], 0, 0, 0);
    }
}

#define BACC_INIT()                                         \
    f32x4 zf = {0.f, 0.f, 0.f, 0.f};                        \
    f32x4 acc[4][2];                                        \
    _Pragma("unroll") for (int i_ = 0; i_ < 4; ++i_) {      \
        acc[i_][0] = zf; acc[i_][1] = zf; }

#define SLOT_A(i) int sb = (wave * 4 + (i)) * 64; int s = sb + lane; \
                  int r = s >> 3, kb = s & 7; int koff = ((kb ^ (r & 7)) << 3);
#define SLOT_B(i) int sb = (wave * 2 + (i)) * 64; int s = sb + lane; \
                  int r = s >> 3, kb = s & 7; int koff = ((kb ^ (r & 7)) << 3);

// ===========================================================================
// small 64^2 helpers
// ===========================================================================
__device__ __forceinline__ void stage_rows(_Float16* dst, const _Float16* __restrict__ src,
                                           int ld, int row0, int k0, int tid) {
#pragma unroll
    for (int i = 0; i < 2; ++i) {
        int s = tid * 2 + i;
        int r = s >> 3, off = (s & 7) << 3;
        *(half8*)(dst + r * LDSP + off) =
            *(const half8*)(src + (size_t)(row0 + r) * ld + k0 + off);
    }
}
__device__ __forceinline__ void mfma_tile(const _Float16* As, const _Float16* Bs,
                                          f32x4 acc[2][2], int wm, int wn, int x, int qq) {
#pragma unroll
    for (int ks = 0; ks < 2; ++ks) {
        int kof = ks * 32 + qq * 8;
        half8 a0 = *(const half8*)(As + (wm + x) * LDSP + kof);
        half8 a1 = *(const half8*)(As + (wm + 16 + x) * LDSP + kof);
        half8 b0 = *(const half8*)(Bs + (wn + x) * LDSP + kof);
        half8 b1 = *(const half8*)(Bs + (wn + 16 + x) * LDSP + kof);
        acc[0][0] = __builtin_amdgcn_mfma_f32_16x16x32_f16(a0, b0, acc[0][0], 0, 0, 0);
        acc[0][1] = __builtin_amdgcn_mfma_f32_16x16x32_f16(a0, b1, acc[0][1], 0, 0, 0);
        acc[1][0] = __builtin_amdgcn_mfma_f32_16x16x32_f16(a1, b0, acc[1][0], 0, 0, 0);
        acc[1][1] = __builtin_amdgcn_mfma_f32_16x16x32_f16(a1, b1, acc[1][1], 0, 0, 0);
    }
}
#define WAVE_IDX()                             \
    int tid = threadIdx.x;                     \
    int wave = tid >> 6, lane = tid & 63;      \
    int wm = (wave >> 1) * 32, wn = (wave & 1) * 32; \
    int x = lane & 15, qq = lane >> 4;
#define ACC_INIT()                             \
    f32x4 zf = {0.f, 0.f, 0.f, 0.f};           \
    f32x4 acc[2][2];                           \
    acc[0][0] = zf; acc[0][1] = zf; acc[1][0] = zf; acc[1][1] = zf;

// ------------------------- prep kernels -------------------------
__global__ __launch_bounds__(256) void k_cast_multi(const float* __restrict__ s0,
                                                    const float* __restrict__ s1,
                                                    const float* __restrict__ s2,
                                                    _Float16* __restrict__ d0,
                                                    _Float16* __restrict__ d1,
                                                    _Float16* __restrict__ d2, int n) {
    const float* s = blockIdx.y == 0 ? s0 : (blockIdx.y == 1 ? s1 : s2);
    _Float16* d = blockIdx.y == 0 ? d0 : (blockIdx.y == 1 ? d1 : d2);
    for (int i = blockIdx.x * 256 + threadIdx.x; i < n; i += gridDim.x * 256)
        d[i] = (_Float16)s[i];
}

__global__ __launch_bounds__(256) void k_repack_conv2(const float* __restrict__ w1,
                                                      const float* __restrict__ w2,
                                                      _Float16* __restrict__ d1,
                                                      _Float16* __restrict__ d2) {
    const float* w = blockIdx.y ? w2 : w1;
    _Float16* dst = blockIdx.y ? d2 : d1;
    int i = blockIdx.x * 256 + threadIdx.x;
    if (i >= 9 * CC * CC) return;
    int r = i / (CC * CC);
    int rem = i - r * CC * CC;
    int co = rem / CC, ci = rem - (rem / CC) * CC;
    dst[i] = (_Float16)w[((size_t)co * CC + ci) * 9 + r];
}

__global__ __launch_bounds__(256) void k_transpose_x(const float* __restrict__ x,
                                                     _Float16* __restrict__ xT) {
    __shared__ float tile[32][33];
    int b = blockIdx.z;
    int c0 = blockIdx.y * 32, n0 = blockIdx.x * 32;
    int tx = threadIdx.x & 31, ty = threadIdx.x >> 5;
    const float* xb = x + (size_t)b * CC * NN;
#pragma unroll
    for (int rr = 0; rr < 32; rr += 8)
        tile[ty + rr][tx] = xb[(size_t)(c0 + ty + rr) * NN + n0 + tx];
    __syncthreads();
    _Float16* xTb = xT + (size_t)b * NN * CC;
#pragma unroll
    for (int rr = 0; rr < 32; rr += 8)
        xTb[(size_t)(n0 + ty + rr) * CC + c0 + tx] = (_Float16)tile[tx][ty + rr];
}

// ------------------------- q/k projection -------------------------
__global__ __launch_bounds__(256) void k_qkproj(const _Float16* __restrict__ Wq,
                                                const _Float16* __restrict__ Wk,
                                                const float* __restrict__ bq,
                                                const float* __restrict__ bk,
                                                const _Float16* __restrict__ xT,
                                                _Float16* __restrict__ qT,
                                                _Float16* __restrict__ kT) {
    __shared__ _Float16 As[64 * LDSP];
    __shared__ _Float16 Bs[64 * LDSP];
    WAVE_IDX();
    int j0 = blockIdx.x * 64, b = blockIdx.z;
    const _Float16* Wp = blockIdx.y ? Wk : Wq;
    const float* bias = blockIdx.y ? bk : bq;
    _Float16* outT = blockIdx.y ? kT : qT;
    const _Float16* xTb = xT + (size_t)b * NN * CC;
    ACC_INIT();
    for (int kc = 0; kc < CC; kc += 64) {
        stage_rows(As, Wp, CC, 0, kc, tid);
        stage_rows(Bs, xTb, CC, j0, kc, tid);
        __syncthreads();
        mfma_tile(As, Bs, acc, wm, wn, x, qq);
        __syncthreads();
    }
#pragma unroll
    for (int ms = 0; ms < 2; ++ms) {
        int R0 = wm + ms * 16 + qq * 4;
#pragma unroll
        for (int ns = 0; ns < 2; ++ns) {
            int Ccol = j0 + wn + ns * 16 + x;
            half4 t;
            t.x = (_Float16)(acc[ms][ns][0] + bias[R0 + 0]);
            t.y = (_Float16)(acc[ms][ns][1] + bias[R0 + 1]);
            t.z = (_Float16)(acc[ms][ns][2] + bias[R0 + 2]);
            t.w = (_Float16)(acc[ms][ns][3] + bias[R0 + 3]);
            *(half4*)(outT + ((size_t)b * NN + Ccol) * DDQ + R0) = t;
        }
    }
}

// ------------------------- C x C GEMM, big tile (out: bf16) -------------------------
// Counted-vmcnt 2-deep pipeline + XCD chunking. Gate read as fp16 from padded buf.
template <int EPI, int PAD>
__global__ __launch_bounds__(256) void k_cgemm(const _Float16* __restrict__ W,
                                               const float* __restrict__ bias,
                                               const _Float16* __restrict__ Bsrc,
                                               const _Float16* __restrict__ gateH,
                                               unsigned short* __restrict__ out) {
    __shared__ __align__(16) _Float16 As[2][128 * 64];
    __shared__ __align__(16) _Float16 Bs[2][64 * 64];
    BWAVE_IDX();
    BIG_DECODE();
    const _Float16* Bb = Bsrc + (size_t)b * (PAD ? (size_t)PROWS * CC : (size_t)NN * CC);

    const _Float16* aSrc[4]; int aOf[4];
#pragma unroll
    for (int i = 0; i < 4; ++i) {
        SLOT_A(i);
        aSrc[i] = W + (size_t)(i0 + r) * CC + koff;
        aOf[i] = sb * 8;
    }
    const _Float16* bSrc[2]; int bOf[2];
#pragma unroll
    for (int i = 0; i < 2; ++i) {
        SLOT_B(i);
        int row = PAD ? prow(j0 + r) : (j0 + r);
        bSrc[i] = Bb + (size_t)row * CC + koff;
        bOf[i] = sb * 8;
    }
    BACC_INIT();
#define STG_G(kc, nb)                                                          \
    { _Pragma("unroll") for (int i = 0; i < 4; ++i)                            \
          gl16(aSrc[i] + (kc), As[nb] + aOf[i]);                               \
      _Pragma("unroll") for (int i = 0; i < 2; ++i)                            \
          gl16(bSrc[i] + (kc), Bs[nb] + bOf[i]); }
    STG_G(0, 0);
    STG_G(64, 1);
    const int NSTEP = CC / 64;   // 8
#pragma unroll
    for (int t = 0; t + 2 < NSTEP; ++t) {   // t = 0..5
        WAIT6();                            // stage(t) landed; stage(t+1) in flight
        BAR();
        btile(As[t & 1], Bs[t & 1], acc, wm, wn, x, qq);
        BAR();
        STG_G((t + 2) * 64, (t & 1));       // prefetch 2 ahead into freed buffer
    }
    WAIT6();
    BAR();
    btile(As[(NSTEP - 2) & 1], Bs[(NSTEP - 2) & 1], acc, wm, wn, x, qq);
    WAIT0();
    BAR();
    btile(As[(NSTEP - 1) & 1], Bs[(NSTEP - 1) & 1], acc, wm, wn, x, qq);
#undef STG_G
#pragma unroll
    for (int mt = 0; mt < 4; ++mt) {
        int R0 = i0 + wm + mt * 16 + qq * 4;
#pragma unroll
        for (int nt = 0; nt < 2; ++nt) {
            int Ccol = j0 + wn + nt * 16 + x;
            half4 gh;
            if (EPI == 1)
                gh = *(const half4*)(gateH + ((size_t)b * PROWS + prow(Ccol)) * CC + R0);
#pragma unroll
            for (int e = 0; e < 4; ++e) {
                float v = acc[mt][nt][e] + bias[R0 + e];
                size_t idx = ((size_t)b * CC + R0 + e) * NN + Ccol;
                if (EPI == 1) v = (float)gh[e] / (1.f + __expf(-v));
                out[idx] = f2bf(v);
            }
        }
    }
}

// ------------------------- energy -> exp -> bf16 + row sums -------------------------
__global__ __launch_bounds__(256) void k_exp(const _Float16* __restrict__ qT,
                                             const _Float16* __restrict__ kT,
                                             unsigned short* __restrict__ attnB,
                                             float* __restrict__ rowsum, int rad) {
    __shared__ _Float16 qs[64 * LDSP];
    __shared__ _Float16 ks[64 * LDSP];
    __shared__ unsigned short Eh[64 * 72];
    __shared__ float psum[512];
    WAVE_IDX();
    int j0 = blockIdx.x * 64, i0 = blockIdx.y * 64, b = blockIdx.z;
    if (rad > 0) {
        int hlo = i0 / WW, hhi = (i0 + 63) / WW;
        int h2lo = imax(0, hlo - rad), h2hi = imin(HH - 1, hhi + rad);
        int klo = (h2lo * WW) & ~63;
        int khi = imin(NN, ((h2hi + 1) * WW + 63) & ~63);
        if (j0 + 64 <= klo || j0 >= khi) return;
    }
    stage_rows(qs, qT + (size_t)b * NN * DDQ, DDQ, i0, 0, tid);
    stage_rows(ks, kT + (size_t)b * NN * DDQ, DDQ, j0, 0, tid);
    __syncthreads();
    ACC_INIT();
    mfma_tile(qs, ks, acc, wm, wn, x, qq);
#pragma unroll
    for (int ns = 0; ns < 2; ++ns) {
        int col = wn + ns * 16 + x;
        int gn = j0 + col;
        int hn = gn / WW, cn = gn % WW;
#pragma unroll
        for (int ms = 0; ms < 2; ++ms)
#pragma unroll
            for (int e = 0; e < 4; ++e) {
                int row = wm + ms * 16 + qq * 4 + e;
                int gm = i0 + row;
                bool valid = true;
                if (rad > 0) {
                    int dh = gm / WW - hn; if (dh < 0) dh = -dh;
                    int dc = gm % WW - cn; if (dc < 0) dc = -dc;
                    valid = (dh <= rad) && (dc <= rad);
                }
                float w = valid ? __expf(acc[ms][ns][e]) : 0.f;
                Eh[row * 72 + col] = f2bf(w);
            }
    }
    __syncthreads();
#pragma unroll
    for (int t = 0; t < 2; ++t) {
        int s = tid + t * 256;
        int r = s >> 3, cg = (s & 7) << 3;
        bf16x8 v = *(const bf16x8*)(Eh + r * 72 + cg);
        *(bf16x8*)(attnB + ((size_t)b * NN + i0 + r) * NN + j0 + cg) = v;
        float ss = 0.f;
#pragma unroll
        for (int j = 0; j < 8; ++j) ss += bf2f((unsigned short)v[j]);
        psum[s] = ss;
    }
    __syncthreads();
    if (tid < 64) {
        float tot = 0.f;
#pragma unroll
        for (int g = 0; g < 8; ++g) tot += psum[tid * 8 + g];
        atomicAdd(rowsum + (size_t)b * NN + i0 + tid, tot);
    }
}

// ------------------------- attention apply, big tile, bf16 -------------------------
// Counted-vmcnt 2-deep pipeline + XCD chunking. res: fp32 (resF) or padded fp16 (resH).
__global__ __launch_bounds__(256) void k_attn(const unsigned short* __restrict__ A,
                                              const unsigned short* __restrict__ attnB,
                                              const float* __restrict__ rowsum,
                                              const float* __restrict__ resF,
                                              const _Float16* __restrict__ resH,
                                              const float* __restrict__ gamma,
                                              float* __restrict__ outF,
                                              _Float16* __restrict__ outT, int rad) {
    __shared__ __align__(16) unsigned short As[2][128 * 64];
    __shared__ __align__(16) unsigned short Bs[2][64 * 64];
    BWAVE_IDX();
    BIG_DECODE();
    int klo = 0, khi = NN;
    if (rad > 0) {
        int hlo = j0 / WW, hhi = (j0 + 63) / WW;
        int h2lo = imax(0, hlo - rad), h2hi = imin(HH - 1, hhi + rad);
        klo = (h2lo * WW) & ~63;
        khi = imin(NN, ((h2hi + 1) * WW + 63) & ~63);
    }
    const unsigned short* Ab = A + (size_t)b * CC * NN;
    const unsigned short* Tb = attnB + (size_t)b * NN * NN;

    const unsigned short* aSrc[4]; int aOf[4];
#pragma unroll
    for (int i = 0; i < 4; ++i) {
        SLOT_A(i);
        aSrc[i] = Ab + (size_t)(i0 + r) * NN + koff + klo;
        aOf[i] = sb * 8;
    }
    const unsigned short* bSrc[2]; int bOf[2];
#pragma unroll
    for (int i = 0; i < 2; ++i) {
        SLOT_B(i);
        bSrc[i] = Tb + (size_t)(j0 + r) * NN + koff + klo;
        bOf[i] = sb * 8;
    }
    BACC_INIT();
    int nsteps = (khi - klo) >> 6;
#define STG_T(kc, nb)                                                          \
    { _Pragma("unroll") for (int i = 0; i < 4; ++i)                            \
          gl16(aSrc[i] + (kc), As[nb] + aOf[i]);                               \
      _Pragma("unroll") for (int i = 0; i < 2; ++i)                            \
          gl16(bSrc[i] + (kc), Bs[nb] + bOf[i]); }
    STG_T(0, 0);
    STG_T(64, 1);
    for (int t = 0; t + 2 < nsteps; ++t) {
        WAIT6();
        BAR();
        btile_b(As[t & 1], Bs[t & 1], acc, wm, wn, x, qq);
        BAR();
        STG_T((t + 2) << 6, (t & 1));
    }
    WAIT6();
    BAR();
    btile_b(As[(nsteps - 2) & 1], Bs[(nsteps - 2) & 1], acc, wm, wn, x, qq);
    WAIT0();
    BAR();
    btile_b(As[(nsteps - 1) & 1], Bs[(nsteps - 1) & 1], acc, wm, wn, x, qq);
#undef STG_T
    float g = gamma[0];
#pragma unroll
    for (int mt = 0; mt < 4; ++mt) {
        int R0 = i0 + wm + mt * 16 + qq * 4;
#pragma unroll
        for (int nt = 0; nt < 2; ++nt) {
            int Ccol = j0 + wn + nt * 16 + x;
            float linv = g / fmaxf(rowsum[(size_t)b * NN + Ccol], 1e-30f);
            float v[4];
            if (resH) {
                half4 rh = *(const half4*)(resH + ((size_t)b * PROWS + prow(Ccol)) * CC + R0);
#pragma unroll
                for (int e = 0; e < 4; ++e)
                    v[e] = acc[mt][nt][e] * linv + (float)rh[e];
            } else {
#pragma unroll
                for (int e = 0; e < 4; ++e)
                    v[e] = acc[mt][nt][e] * linv + resF[((size_t)b * CC + R0 + e) * NN + Ccol];
            }
            if (outT) {
                half4 t;
                t.x = (_Float16)v[0]; t.y = (_Float16)v[1];
                t.z = (_Float16)v[2]; t.w = (_Float16)v[3];
                *(half4*)(outT + ((size_t)b * PROWS + prow(Ccol)) * CC + R0) = t;
            }
            if (outF) {
#pragma unroll
                for (int e = 0; e < 4; ++e)
                    outF[((size_t)b * CC + R0 + e) * NN + Ccol] = v[e];
            }
        }
    }
}

// ------------------------- 3x3 conv, big tile, fused BN+ReLU -------------------------
// Counted-vmcnt 2-deep pipeline over flattened 72 (tap x kc) steps + XCD chunking.
// outF (fp32 residual copy) optional: conv1 skips it.
__global__ __launch_bounds__(256) void k_conv3(const _Float16* __restrict__ Arep,
                                               const _Float16* __restrict__ Tpad,
                                               const float* __restrict__ bng,
                                               const float* __restrict__ bnb,
                                               const float* __restrict__ bnm,
                                               const float* __restrict__ bnv,
                                               float* __restrict__ outF,
                                               _Float16* __restrict__ outT) {
    __shared__ __align__(16) _Float16 As[2][128 * 64];
    __shared__ __align__(16) _Float16 Bs[2][64 * 64];
    BWAVE_IDX();
    BIG_DECODE();
    const _Float16* Tb = Tpad + (size_t)b * PROWS * CC;

    const _Float16* aBase[4]; int aOf[4];
#pragma unroll
    for (int i = 0; i < 4; ++i) {
        SLOT_A(i);
        aBase[i] = Arep + (size_t)(i0 + r) * CC + koff;
        aOf[i] = sb * 8;
    }
    const _Float16* bBase[2]; int bOf[2];
#pragma unroll
    for (int i = 0; i < 2; ++i) {
        SLOT_B(i);
        bBase[i] = Tb + (size_t)prow(j0 + r) * CC + koff;
        bOf[i] = sb * 8;
    }
    BACC_INIT();

#define STAGE_CONV(u, nb)                                                       \
    {                                                                           \
        int rt_ = (u) >> 3, ci_ = ((u) & 7) << 6;                               \
        int r3_ = rt_ / 3;                                                      \
        ptrdiff_t aoff_ = (ptrdiff_t)rt_ * (CC * CC) + ci_;                     \
        ptrdiff_t boff_ =                                                       \
            (ptrdiff_t)((r3_ - 1) * PW + (rt_ - r3_ * 3 - 1)) * CC + ci_;       \
        _Pragma("unroll") for (int i = 0; i < 4; ++i)                           \
            gl16(aBase[i] + aoff_, As[nb] + aOf[i]);                            \
        _Pragma("unroll") for (int i = 0; i < 2; ++i)                           \
            gl16(bBase[i] + boff_, Bs[nb] + bOf[i]);                            \
    }

    STAGE_CONV(0, 0);
    STAGE_CONV(1, 1);
    const int TOT = 9 * (CC / 64);   // 72
#pragma unroll 2
    for (int t = 0; t + 2 < TOT; ++t) {   // t = 0..69 (even count, parity static)
        WAIT6();
        BAR();
        btile(As[t & 1], Bs[t & 1], acc, wm, wn, x, qq);
        BAR();
        STAGE_CONV(t + 2, (t & 1));
    }
    WAIT6();
    BAR();
    btile(As[(TOT - 2) & 1], Bs[(TOT - 2) & 1], acc, wm, wn, x, qq);
    WAIT0();
    BAR();
    btile(As[(TOT - 1) & 1], Bs[(TOT - 1) & 1], acc, wm, wn, x, qq);
#undef STAGE_CONV

#pragma unroll
    for (int mt = 0; mt < 4; ++mt) {
        int R0 = i0 + wm + mt * 16 + qq * 4;
        float sc[4], sh[4];
#pragma unroll
        for (int e = 0; e < 4; ++e) {
            sc[e] = bng[R0 + e] * rsqrtf(bnv[R0 + e] + 1e-5f);
            sh[e] = bnb[R0 + e] - bnm[R0 + e] * sc[e];
        }
#pragma unroll
        for (int nt = 0; nt < 2; ++nt) {
            int Ccol = j0 + wn + nt * 16 + x;
            float v[4];
#pragma unroll
            for (int e = 0; e < 4; ++e) {
                float t = acc[mt][nt][e] * sc[e] + sh[e];
                v[e] = t > 0.f ? t : 0.f;
            }
            if (outF) {
#pragma unroll
                for (int e = 0; e < 4; ++e)
                    outF[((size_t)b * CC + R0 + e) * NN + Ccol] = v[e];
            }
            half4 t4;
            t4.x = (_Float16)v[0]; t4.y = (_Float16)v[1];
            t4.z = (_Float16)v[2]; t4.w = (_Float16)v[3];
            *(half4*)(outT + ((size_t)b * PROWS + prow(Ccol)) * CC + R0) = t4;
        }
    }
}

// ---------------------------------------------------------------------------
extern "C" void kernel_launch(void* const* d_in, const int* in_sizes, int n_in,
                              void* d_out, int out_size, void* d_ws, size_t ws_size,
                              hipStream_t stream) {
    const float* xin  = (const float*)d_in[0];
    const float* Wq   = (const float*)d_in[1];
    const float* bq   = (const float*)d_in[2];
    const float* Wk   = (const float*)d_in[3];
    const float* bk   = (const float*)d_in[4];
    const float* Wv   = (const float*)d_in[5];
    const float* bv   = (const float*)d_in[6];
    const float* c1w  = (const float*)d_in[7];
    const float* bn1w = (const float*)d_in[8];
    const float* bn1b = (const float*)d_in[9];
    const float* bn1m = (const float*)d_in[10];
    const float* bn1v = (const float*)d_in[11];
    const float* c2w  = (const float*)d_in[12];
    const float* bn2w = (const float*)d_in[13];
    const float* bn2b = (const float*)d_in[14];
    const float* bn2m = (const float*)d_in[15];
    const float* bn2v = (const float*)d_in[16];
    const float* s1w  = (const float*)d_in[17];
    const float* s1b  = (const float*)d_in[18];
    const float* s2w  = (const float*)d_in[19];
    const float* s2b  = (const float*)d_in[20];
    const float* gamma  = (const float*)d_in[21];
    const float* gamma1 = (const float*)d_in[22];
    const float* gamma2 = (const float*)d_in[23];

    float* out = (float*)d_out;

    char* p = (char*)d_ws;
    unsigned short* attn = (unsigned short*)p; p += (size_t)BB * NN * NN * 2;  // 42.5 MB
    _Float16* xT    = (_Float16*)p; p += (size_t)BB * NN * CC * 2;      // 9.4 MB
    _Float16* qT    = (_Float16*)p; p += (size_t)BB * NN * DDQ * 2;
    _Float16* kT    = (_Float16*)p; p += (size_t)BB * NN * DDQ * 2;
    unsigned short* vsB = (unsigned short*)p; p += (size_t)BB * CC * NN * 2;  // 9.4 MB
    _Float16* TattnP= (_Float16*)p; p += (size_t)BB * PROWS * CC * 2;   // 10.2 MB
    _Float16* TconvP= (_Float16*)p; p += (size_t)BB * PROWS * CC * 2;   // 10.2 MB
    float*    rR    = (float*)p;    p += (size_t)BB * CC * NN * 4;      // 18.9 MB
    _Float16* wq_h  = (_Float16*)p; p += (size_t)DDQ * CC * 2;
    _Float16* wk_h  = (_Float16*)p; p += (size_t)DDQ * CC * 2;
    _Float16* wv_h  = (_Float16*)p; p += (size_t)CC * CC * 2;
    _Float16* s1_h  = (_Float16*)p; p += (size_t)CC * CC * 2;
    _Float16* s2_h  = (_Float16*)p; p += (size_t)CC * CC * 2;
    _Float16* crep1 = (_Float16*)p; p += (size_t)9 * CC * CC * 2;
    _Float16* crep2 = (_Float16*)p; p += (size_t)9 * CC * CC * 2;
    float*    rowsum= (float*)p;    p += (size_t)3 * BB * NN * 4;       // 110 KB (3 stages)

    dim3 blk(256);

    // zero padded activation borders + rowsums
    hipMemsetAsync(TattnP, 0, (size_t)BB * PROWS * CC * 2, stream);
    hipMemsetAsync(TconvP, 0, (size_t)BB * PROWS * CC * 2, stream);
    hipMemsetAsync(rowsum, 0, (size_t)3 * BB * NN * 4, stream);

    // ---- prep ----
    k_cast_multi<<<dim3(128, 2), blk, 0, stream>>>(Wq, Wk, nullptr, wq_h, wk_h, nullptr, DDQ * CC);
    k_cast_multi<<<dim3(1024, 3), blk, 0, stream>>>(Wv, s1w, s2w, wv_h, s1_h, s2_h, CC * CC);
    k_repack_conv2<<<dim3((9 * CC * CC + 255) / 256, 2), blk, 0, stream>>>(c1w, c2w, crep1, crep2);
    k_transpose_x<<<dim3(NN / 32, CC / 32, BB), blk, 0, stream>>>(xin, xT);

    dim3 gQK(NN / 64, 2, BB);
    dim3 gExp(NN / 64, NN / 64, BB);    // (36, 36, 4) = 5184 blocks
    dim3 gBig(576);                     // 1-D, XCD-chunk swizzled in-kernel

    float* rs0 = rowsum;
    float* rs1 = rowsum + (size_t)BB * NN;
    float* rs2 = rowsum + (size_t)2 * BB * NN;

    // projections
    k_qkproj<<<gQK, blk, 0, stream>>>(wq_h, wk_h, bq, bk, xT, qT, kT);
    k_cgemm<0, 0><<<gBig, blk, 0, stream>>>(wv_h, bv, xT, nullptr, vsB);

    // ---- stage 0: dense attention ----
    k_exp<<<gExp, blk, 0, stream>>>(qT, kT, attn, rs0, -1);
    k_attn<<<gBig, blk, 0, stream>>>(vsB, attn, rs0, xin, nullptr, gamma, nullptr, TattnP, -1);
    k_conv3<<<gBig, blk, 0, stream>>>(crep1, TattnP, bn1w, bn1b, bn1m, bn1v, nullptr, TconvP);

    // ---- stage 1: radius-6 masked attention ----
    k_cgemm<1, 1><<<gBig, blk, 0, stream>>>(s1_h, s1b, TconvP, TconvP, vsB);
    k_exp<<<gExp, blk, 0, stream>>>(qT, kT, attn, rs1, 6);
    k_attn<<<gBig, blk, 0, stream>>>(vsB, attn, rs1, nullptr, TconvP, gamma1, nullptr, TattnP, 6);
    k_conv3<<<gBig, blk, 0, stream>>>(crep2, TattnP, bn2w, bn2b, bn2m, bn2v, rR, TconvP);

    // ---- stage 2: radius-12 masked attention ----
    k_cgemm<1, 1><<<gBig, blk, 0, stream>>>(s2_h, s2b, TconvP, TconvP, vsB);
    k_exp<<<gExp, blk, 0, stream>>>(qT, kT, attn, rs2, 12);
    k_attn<<<gBig, blk, 0, stream>>>(vsB, attn, rs2, rR, nullptr, gamma2, out, nullptr, 12);
}